// Round 10
// baseline (217.157 us; speedup 1.0000x reference)
//
#include <hip/hip_runtime.h>
#include <float.h>
#include <stdint.h>

// B=8, N=4096, S=1024 queries/batch, K=32 neighbors
#define TOT   262144      // 8*1024*32 grouped elements
#define NPTS  4096
#define KNN   32
#define BN_EPS 1e-5f
#define CAPV  64          // kNN fast-path candidate capacity (1 per lane)

typedef _Float16 f16;
typedef _Float16 f16x2 __attribute__((ext_vector_type(2)));
typedef _Float16 f16x4 __attribute__((ext_vector_type(4)));
typedef _Float16 f16x8 __attribute__((ext_vector_type(8)));
typedef float    f32x4 __attribute__((ext_vector_type(4)));

__device__ __forceinline__ int mbcnt64(unsigned long long m){
  return __builtin_amdgcn_mbcnt_hi((unsigned)(m>>32),
         __builtin_amdgcn_mbcnt_lo((unsigned)(m & 0xffffffffull), 0));
}
__device__ __forceinline__ unsigned f2ord(float f){
  unsigned u = __float_as_uint(f);
  return u ^ (((unsigned)((int)u >> 31)) | 0x80000000u);
}
// packed bn+relu on 2 f16 halves
__device__ __forceinline__ f16x2 bnrelu2(f16x2 x, f16x2 a, f16x2 c){
  f16x2 r = x*a + c;
  const f16 z = (f16)0.f;
  r[0] = r[0] > z ? r[0] : z;
  r[1] = r[1] > z ? r[1] : z;
  return r;
}
// write one gathered element: SoA f16 (for stats gram) + [elem][16] (MFMA B-frags)
__device__ __forceinline__ void writeElem(int n, int e, float qx, float qy, float qz,
    const float4* __restrict__ xb, const float* __restrict__ fb,
    f16* __restrict__ grouped, f16* __restrict__ g16){
  float4 P = xb[n];
  f16 a[16];
  a[0]=(f16)(P.x-qx); a[1]=(f16)(P.y-qy); a[2]=(f16)(P.z-qz);
  #pragma unroll
  for (int c6=0;c6<6;c6++) a[3+c6] = (f16)fb[n*6+c6];
  #pragma unroll
  for (int i=9;i<16;i++) a[i]=(f16)0.f;
  #pragma unroll
  for (int c=0;c<9;c++) grouped[c*TOT+e] = a[c];
  f16x8 lo, hi;
  #pragma unroll
  for (int i=0;i<8;i++){ lo[i]=a[i]; hi[i]=a[8+i]; }
  *(f16x8*)(g16 + (size_t)e*16)     = lo;
  *(f16x8*)(g16 + (size_t)e*16 + 8) = hi;
}

// P0: xyz -> float4 {x,y,z,|p|^2}
__global__ __launch_bounds__(256) void prep(const float* __restrict__ xyz,
    float4* __restrict__ xyzp){
  int p = blockIdx.x*256 + threadIdx.x;            // 32768 points
  float x = xyz[p*3+0], y = xyz[p*3+1], z = xyz[p*3+2];
  xyzp[p] = make_float4(x, y, z, x*x+y*y+z*z);
}

// K1: block = 4 waves = 8 queries (2/wave), grid 1024 (16 waves/CU).
// Points staged through a 16KB LDS tile (4 tiles x 1024 pts), distance loop
// reads LDS not L2. Pass A: per-lane min (float cmp, no f2ord) -> joint
// bitonic -> Uf = 32nd smallest minimum (upper bound). Pass B: re-stage
// tiles, LDS-atomic compact of d<=Uf. Then joint u64 bitonic of
// (f2ord(d),idx) -> exact top-32 with jax.lax.top_k tie order.
__global__ __launch_bounds__(256) void knn_gather(
    const float4* __restrict__ xyzp, const float* __restrict__ pts,
    f16* __restrict__ grouped, f16* __restrict__ g16,
    float* __restrict__ out_newxyz){
  __shared__ float4 tile[1024];
  __shared__ unsigned wk[8][CAPV];
  __shared__ unsigned short wi[8][CAPV];
  __shared__ unsigned lcnt[8];
  const int tid = threadIdx.x, lane = tid & 63, wv = tid >> 6;
  const int q0 = blockIdx.x*8 + wv*2;              // wave's 2 queries
  const int b  = (blockIdx.x*8) >> 10;             // same batch for block
  const float4* xb = xyzp + b*NPTS;
  float qx[2],qy[2],qz[2],qq[2];
  #pragma unroll
  for (int t=0;t<2;t++){
    int s = (q0+t) & 1023;
    float4 Q = xb[s*4];
    qx[t]=Q.x; qy[t]=Q.y; qz[t]=Q.z; qq[t]=Q.w;
  }
  if (tid < 8) lcnt[tid] = 0;
  if (lane == 0){
    #pragma unroll
    for (int t=0;t<2;t++){
      out_newxyz[(q0+t)*3+0]=qx[t]; out_newxyz[(q0+t)*3+1]=qy[t];
      out_newxyz[(q0+t)*3+2]=qz[t];
    }
  }

  // pass A: per-lane min distance over this lane's 64 points (4 tiles x 16)
  float dmin[2] = {FLT_MAX, FLT_MAX};
  #pragma unroll 1
  for (int tl=0; tl<4; ++tl){
    __syncthreads();
    #pragma unroll
    for (int i=0;i<4;i++) tile[i*256+tid] = xb[tl*1024 + i*256 + tid];
    __syncthreads();
    #pragma unroll 4
    for (int i=0;i<16;i++){
      float4 P = tile[i*64+lane];
      #pragma unroll
      for (int t=0;t<2;t++){
        float d = (qq[t]+P.w) - 2.f*(qx[t]*P.x+qy[t]*P.y+qz[t]*P.z);
        dmin[t] = d < dmin[t] ? d : dmin[t];
      }
    }
  }
  // joint float bitonic sort of minima ascending
  float sm[2] = {dmin[0], dmin[1]};
  #pragma unroll
  for (int k=2;k<=64;k<<=1){
    #pragma unroll
    for (int j=k>>1;j>0;j>>=1){
      bool keepmin = (((lane&k)==0) == ((lane&j)==0));
      #pragma unroll
      for (int t=0;t<2;t++){
        float o = __shfl_xor(sm[t], j, 64);
        sm[t] = keepmin ? fminf(sm[t],o) : fmaxf(sm[t],o);
      }
    }
  }
  float Uf[2];
  #pragma unroll
  for (int t=0;t<2;t++) Uf[t] = __shfl(sm[t], 31, 64);

  // pass B: re-stage tiles; compact candidates d<=Uf (order-free)
  #pragma unroll 1
  for (int tl=0; tl<4; ++tl){
    __syncthreads();
    #pragma unroll
    for (int i=0;i<4;i++) tile[i*256+tid] = xb[tl*1024 + i*256 + tid];
    __syncthreads();
    #pragma unroll 2
    for (int i=0;i<16;i++){
      float4 P = tile[i*64+lane];
      #pragma unroll
      for (int t=0;t<2;t++){
        float d = (qq[t]+P.w) - 2.f*(qx[t]*P.x+qy[t]*P.y+qz[t]*P.z);
        if (d <= Uf[t]){
          unsigned p = atomicAdd(&lcnt[wv*2+t], 1u);
          if (p < CAPV){
            wk[wv*2+t][p] = f2ord(d);
            wi[wv*2+t][p] = (unsigned short)(tl*1024 + i*64 + lane);
          }
        }
      }
    }
  }
  int cnt[2] = {(int)lcnt[wv*2], (int)lcnt[wv*2+1]};

  // joint u64 bitonic of (key<<16)|idx
  unsigned long long v[2];
  #pragma unroll
  for (int t=0;t<2;t++){
    unsigned myk = (lane<cnt[t]) ? wk[wv*2+t][lane] : 0xFFFFFFFFu;
    unsigned myi = (lane<cnt[t]) ? wi[wv*2+t][lane] : 0u;
    v[t] = (((unsigned long long)myk)<<16) | myi;
  }
  #pragma unroll
  for (int k=2;k<=64;k<<=1){
    #pragma unroll
    for (int j=k>>1;j>0;j>>=1){
      bool keepmin = (((lane&k)==0) == ((lane&j)==0));
      #pragma unroll
      for (int t=0;t<2;t++){
        unsigned long long o = __shfl_xor(v[t], j, 64);
        v[t] = keepmin ? (v[t]<o?v[t]:o) : (v[t]>o?v[t]:o);
      }
    }
  }

  const float* fb = pts + (size_t)b*NPTS*6;
  #pragma unroll 1
  for (int t=0;t<2;t++){
    const int ebase = (q0+t)*KNN;
    if (cnt[t] <= CAPV){
      if (lane < KNN){
        int n = (int)(v[t] & 0xffffull);
        writeElem(n, ebase+lane, qx[t],qy[t],qz[t], xb, fb, grouped, g16);
      }
    } else {
      // slow exact path (rare): global rescan, radix bisect + ordered collect
      unsigned V=0;
      for (int bit=31; bit>=0; --bit){
        unsigned X = V | (1u<<bit);
        int c=0;
        for (int j=0;j<64;j++){
          float4 P = xb[j*64+lane];
          float d = (qq[t]+P.w) - 2.f*(qx[t]*P.x+qy[t]*P.y+qz[t]*P.z);
          c += __popcll(__ballot(f2ord(d) < X));
        }
        if (c < KNN) V = X;
      }
      int cnt2=0;
      for (int pass=0; pass<2; ++pass){
        for (int j=0;j<64;j++){
          float4 P = xb[j*64+lane];
          float d = (qq[t]+P.w) - 2.f*(qx[t]*P.x+qy[t]*P.y+qz[t]*P.z);
          unsigned kk = f2ord(d);
          bool sel = pass ? (kk==V) : (kk<V);
          unsigned long long msk = __ballot(sel);
          int pos = cnt2 + mbcnt64(msk);
          if (sel && pos < KNN)
            writeElem(j*64+lane, ebase+pos, qx[t],qy[t],qz[t], xb, fb, grouped, g16);
          cnt2 += __popcll(msk);
        }
      }
    }
  }
}

// K2: second-moment matrix via MFMA gram. G' = [g(9ch), 1]; M = G'^T G'.
// Coverage: 128 blocks x 4 waves x 16 chunks x 32 elems = 262144 = TOT.
__global__ __launch_bounds__(256) void stats0m(const f16* __restrict__ grouped,
    float* __restrict__ s0m){
  const int lane = threadIdx.x & 63, wv = threadIdx.x >> 6;
  const int c = lane & 15, q = lane >> 4;
  const int base = (blockIdx.x*4 + wv)*512;        // 512 elems per wave
  f16x8 cfill = {};
  if (c == 9){
    #pragma unroll
    for (int i=0;i<8;i++) cfill[i] = (f16)1.f;
  }
  f32x4 acc = {0.f,0.f,0.f,0.f};
  #pragma unroll 4
  for (int chunk=0; chunk<16; ++chunk){
    int e = base + chunk*32 + q*8;
    f16x8 f = cfill;
    if (c < 9) f = *(const f16x8*)(grouped + (size_t)c*TOT + e);
    acc = __builtin_amdgcn_mfma_f32_16x16x32_f16(f, f, acc, 0,0,0);
  }
  __shared__ float red[4][16][16];
  #pragma unroll
  for (int i=0;i<4;i++) red[wv][q*4+i][c] = acc[i];
  __syncthreads();
  const int tid = threadIdx.x;
  if (tid < 160){
    int row = tid>>4, col = tid&15;
    float vv = red[0][row][col]+red[1][row][col]+red[2][row][col]+red[3][row][col];
    atomicAdd(&s0m[tid], vv);
  }
}

// K3: M(10x16) -> BN0 coeffs; W0h = a0-folded W0 (f16 [64][32] K-pad); W1h/W2h f16
__global__ void finalize0(const float* __restrict__ s0m,
    const float* __restrict__ W0, const float* __restrict__ g0,
    const float* __restrict__ b0, float* __restrict__ ac0,
    const float* __restrict__ W1, const float* __restrict__ W2,
    f16* __restrict__ W0h, f16* __restrict__ W1h, f16* __restrict__ W2h){
  const int tid = threadIdx.x;                     // 256
  __shared__ float S[160];
  __shared__ float A0s[64];
  if (tid < 160) S[tid] = s0m[tid];
  __syncthreads();
  if (tid < 64){
    float w[9];
    #pragma unroll
    for (int c=0;c<9;c++) w[c]=W0[tid*9+c];
    const float inv = 1.f/(float)TOT;
    float m=0.f;
    #pragma unroll
    for (int c=0;c<9;c++) m = fmaf(w[c], S[c*16+9], m);
    m *= inv;
    float e2=0.f;
    #pragma unroll
    for (int c1=0;c1<9;c1++){
      float t=0.f;
      #pragma unroll
      for (int c2=0;c2<9;c2++) t = fmaf(w[c2], S[c1*16+c2], t);
      e2 = fmaf(w[c1], t, e2);
    }
    e2 *= inv;
    float var = e2 - m*m;
    float a = g0[tid]*rsqrtf(var + BN_EPS);
    ac0[tid]    = a;
    ac0[64+tid] = fmaf(-m, a, b0[tid]);
    A0s[tid]    = a;
  }
  __syncthreads();
  for (int i=tid; i<2048; i+=256){
    int o = i>>5, c = i&31;
    W0h[i] = (f16)(c<9 ? A0s[o]*W0[o*9+c] : 0.f);
  }
  for (int i=tid; i<4096; i+=256) W1h[i] = (f16)W1[i];
  for (int i=tid; i<8192; i+=256) W2h[i] = (f16)W2[i];
}

// K4: BN1-stats only, grid 1024 (4 subs/wave). Weights staged in LDS.
__global__ __launch_bounds__(256) void layer1s(
    const f16* __restrict__ g16, const f16* __restrict__ W0h,
    const f16* __restrict__ W1h, const float* __restrict__ ac0,
    float* __restrict__ s1g){
  __shared__ f16 sW0[2048];
  __shared__ f16 sW1[4096];
  __shared__ float ac0c[64];
  __shared__ f16 hb0[4][16][72];
  __shared__ float sred[4][128];
  const int tid = threadIdx.x;
  const int lane = tid & 63, wv = tid >> 6;
  const int e16 = lane & 15, q = lane >> 4;
  *(f16x8*)(&sW0[tid*8]) = *(const f16x8*)(W0h + tid*8);
  *(f16x8*)(&sW1[tid*8])        = *(const f16x8*)(W1h + tid*8);
  *(f16x8*)(&sW1[2048 + tid*8]) = *(const f16x8*)(W1h + 2048 + tid*8);
  if (tid < 64) ac0c[tid] = ac0[64+tid];
  __syncthreads();

  const int base = blockIdx.x*256 + wv*64;         // grid 1024
  float ssum[16], ssq[16];
  #pragma unroll
  for (int i=0;i<16;i++){ ssum[i]=0.f; ssq[i]=0.f; }

  #pragma unroll 1
  for (int sub=0; sub<4; ++sub){
    int elem = base + sub*16 + e16;
    f16x8 bg = {};
    if (q < 2) bg = *(const f16x8*)(g16 + (size_t)elem*16 + q*8);
    #pragma unroll
    for (int m=0;m<4;m++){
      f32x4 acc = *(const f32x4*)(&ac0c[m*16 + q*4]);
      f16x8 A0f = *(const f16x8*)(&sW0[(m*16+e16)*32 + q*8]);
      acc = __builtin_amdgcn_mfma_f32_16x16x32_f16(A0f, bg, acc, 0,0,0);
      f16x4 w;
      w[0]=(f16)fmaxf(acc[0],0.f); w[1]=(f16)fmaxf(acc[1],0.f);
      w[2]=(f16)fmaxf(acc[2],0.f); w[3]=(f16)fmaxf(acc[3],0.f);
      *(f16x4*)(&hb0[wv][e16][m*16 + q*4]) = w;
    }
    f32x4 acc2[4];
    #pragma unroll
    for (int m=0;m<4;m++) acc2[m] = (f32x4){0.f,0.f,0.f,0.f};
    #pragma unroll
    for (int s=0;s<2;s++){
      f16x8 bh = *(const f16x8*)(&hb0[wv][e16][s*32 + q*8]);
      #pragma unroll
      for (int m=0;m<4;m++){
        f16x8 A1f = *(const f16x8*)(&sW1[(m*16+e16)*64 + s*32 + q*8]);
        acc2[m] = __builtin_amdgcn_mfma_f32_16x16x32_f16(A1f, bh, acc2[m], 0,0,0);
      }
    }
    #pragma unroll
    for (int m=0;m<4;m++)
      #pragma unroll
      for (int i=0;i<4;i++){
        float x = acc2[m][i];
        ssum[m*4+i] += x;
        ssq[m*4+i]  = fmaf(x, x, ssq[m*4+i]);
      }
  }
  #pragma unroll
  for (int t=0;t<16;t++){
    float a = ssum[t], bq = ssq[t];
    #pragma unroll
    for (int off=1; off<16; off<<=1){
      a  += __shfl_xor(a,  off, 64);
      bq += __shfl_xor(bq, off, 64);
    }
    ssum[t]=a; ssq[t]=bq;
  }
  if (e16==0){
    #pragma unroll
    for (int m=0;m<4;m++)
      #pragma unroll
      for (int i=0;i<4;i++){
        int ch = m*16 + q*4 + i;
        sred[wv][ch]    = ssum[m*4+i];
        sred[wv][64+ch] = ssq[m*4+i];
      }
  }
  __syncthreads();
  if (tid < 128){
    float v = sred[0][tid]+sred[1][tid]+sred[2][tid]+sred[3][tid];
    atomicAdd(&s1g[tid], v);
  }
}

// K5: recompute x1 (weights from LDS), BN1+relu, GEMM3 vs W2 in 2 nt-groups
// (acc3 32 VGPR). Grid 1024, 2 queries/wave. Max over k + BN2 stats fused.
__global__ __launch_bounds__(256) void layer2max(
    const f16* __restrict__ g16, const f16* __restrict__ W0h,
    const f16* __restrict__ W1h, const f16* __restrict__ W2h,
    const float* __restrict__ ac0, const float* __restrict__ s1g,
    const float* __restrict__ g1, const float* __restrict__ b1,
    float* __restrict__ maxbuf, float* __restrict__ s2g){
  __shared__ f16 sW0[2048];
  __shared__ f16 sW1[4096];
  __shared__ float ac0c[64];
  __shared__ f16 ac1s[128];
  __shared__ f16 hb0[4][16][72];
  __shared__ f16 hb1[4][2][16][72];
  __shared__ float lds[4][256];
  const int tid = threadIdx.x;
  const int lane = tid & 63, wv = tid >> 6;
  const int e16 = lane & 15, q = lane >> 4;
  *(f16x8*)(&sW0[tid*8]) = *(const f16x8*)(W0h + tid*8);
  *(f16x8*)(&sW1[tid*8])        = *(const f16x8*)(W1h + tid*8);
  *(f16x8*)(&sW1[2048 + tid*8]) = *(const f16x8*)(W1h + 2048 + tid*8);
  if (tid < 64) ac0c[tid] = ac0[64+tid];
  if (tid < 64){
    const float inv = 1.f/(float)TOT;
    float m = s1g[tid]*inv;
    float vv = s1g[64+tid]*inv - m*m;
    float a = g1[tid]*rsqrtf(vv + BN_EPS);
    ac1s[tid]    = (f16)a;
    ac1s[64+tid] = (f16)fmaf(-m, a, b1[tid]);
  }
  __syncthreads();

  f16x8 Bw[8][2];                                  // W2 frags, persistent
  #pragma unroll
  for (int nt=0;nt<8;nt++)
    #pragma unroll
    for (int s=0;s<2;s++) Bw[nt][s] = *(const f16x8*)(W2h + (nt*16+e16)*64 + s*32 + q*8);

  float ssum[8], ssq[8];
  #pragma unroll
  for (int i=0;i<8;i++){ ssum[i]=0.f; ssq[i]=0.f; }

  #pragma unroll 1
  for (int qq=0; qq<2; ++qq){                      // 2 queries per wave
    const int qid = blockIdx.x*8 + wv*2 + qq;
    // phase 1: h1 tiles for mt=0,1 into hb1
    #pragma unroll 1
    for (int mt=0; mt<2; ++mt){
      int elem = qid*32 + mt*16 + e16;
      f16x8 bg = {};
      if (q < 2) bg = *(const f16x8*)(g16 + (size_t)elem*16 + q*8);
      #pragma unroll
      for (int m=0;m<4;m++){
        f32x4 acc = *(const f32x4*)(&ac0c[m*16 + q*4]);
        f16x8 A0f = *(const f16x8*)(&sW0[(m*16+e16)*32 + q*8]);
        acc = __builtin_amdgcn_mfma_f32_16x16x32_f16(A0f, bg, acc, 0,0,0);
        f16x4 w;
        w[0]=(f16)fmaxf(acc[0],0.f); w[1]=(f16)fmaxf(acc[1],0.f);
        w[2]=(f16)fmaxf(acc[2],0.f); w[3]=(f16)fmaxf(acc[3],0.f);
        *(f16x4*)(&hb0[wv][e16][m*16 + q*4]) = w;
      }
      f32x4 acc2[4];
      #pragma unroll
      for (int m=0;m<4;m++) acc2[m] = (f32x4){0.f,0.f,0.f,0.f};
      #pragma unroll
      for (int s=0;s<2;s++){
        f16x8 bh = *(const f16x8*)(&hb0[wv][e16][s*32 + q*8]);
        #pragma unroll
        for (int m=0;m<4;m++){
          f16x8 A1f = *(const f16x8*)(&sW1[(m*16+e16)*64 + s*32 + q*8]);
          acc2[m] = __builtin_amdgcn_mfma_f32_16x16x32_f16(A1f, bh, acc2[m], 0,0,0);
        }
      }
      #pragma unroll
      for (int m=0;m<4;m++){
        f16x4 a4 = *(const f16x4*)(&ac1s[m*16 + q*4]);
        f16x4 c4 = *(const f16x4*)(&ac1s[64 + m*16 + q*4]);
        f16x2 p0 = bnrelu2((f16x2){(f16)acc2[m][0], (f16)acc2[m][1]},
                           (f16x2){a4[0],a4[1]}, (f16x2){c4[0],c4[1]});
        f16x2 p1 = bnrelu2((f16x2){(f16)acc2[m][2], (f16)acc2[m][3]},
                           (f16x2){a4[2],a4[3]}, (f16x2){c4[2],c4[3]});
        f16x4 w; w[0]=p0[0]; w[1]=p0[1]; w[2]=p1[0]; w[3]=p1[1];
        *(f16x4*)(&hb1[wv][mt][e16][m*16 + q*4]) = w;
      }
    }
    // phase 2: GEMM3, nt in 2 groups of 4
    float mx[8];
    #pragma unroll 1
    for (int g=0; g<2; ++g){
      f32x4 acc3[4][2];
      #pragma unroll
      for (int j=0;j<4;j++){ acc3[j][0]=(f32x4){0,0,0,0}; acc3[j][1]=(f32x4){0,0,0,0}; }
      #pragma unroll
      for (int mt=0; mt<2; ++mt)
        #pragma unroll
        for (int s=0;s<2;s++){
          f16x8 af = *(const f16x8*)(&hb1[wv][mt][e16][s*32 + q*8]);
          #pragma unroll
          for (int j=0;j<4;j++)
            acc3[j][mt] = __builtin_amdgcn_mfma_f32_16x16x32_f16(af, Bw[g*4+j][s], acc3[j][mt], 0,0,0);
        }
      #pragma unroll
      for (int j=0;j<4;j++){
        int nt = g*4 + j;
        f32x4 u = acc3[j][0], vv = acc3[j][1];
        float m1 = fmaxf(fmaxf(u[0],u[1]), fmaxf(u[2],u[3]));
        float m2 = fmaxf(fmaxf(vv[0],vv[1]), fmaxf(vv[2],vv[3]));
        float m = fmaxf(m1, m2);
        ssum[nt] += (u[0]+u[1])+(u[2]+u[3]) + (vv[0]+vv[1])+(vv[2]+vv[3]);
        float sq = 0.f;
        #pragma unroll
        for (int i=0;i<4;i++){ sq = fmaf(u[i],u[i],sq); sq = fmaf(vv[i],vv[i],sq); }
        ssq[nt] += sq;
        m = fmaxf(m, __shfl_xor(m, 16, 64));
        m = fmaxf(m, __shfl_xor(m, 32, 64));
        mx[nt] = m;
      }
    }
    if (lane < 16){
      #pragma unroll
      for (int nt=0;nt<8;nt++) maxbuf[(size_t)qid*128 + nt*16 + lane] = mx[nt];
    }
  }
  #pragma unroll
  for (int nt=0;nt<8;nt++){
    ssum[nt] += __shfl_xor(ssum[nt], 16, 64);
    ssum[nt] += __shfl_xor(ssum[nt], 32, 64);
    ssq[nt]  += __shfl_xor(ssq[nt], 16, 64);
    ssq[nt]  += __shfl_xor(ssq[nt], 32, 64);
  }
  if (q==0){
    #pragma unroll
    for (int nt=0;nt<8;nt++){
      lds[wv][nt*16+e16]     = ssum[nt];
      lds[wv][128+nt*16+e16] = ssq[nt];
    }
  }
  __syncthreads();
  float v = lds[0][tid]+lds[1][tid]+lds[2][tid]+lds[3][tid];
  atomicAdd(&s2g[tid], v);
}

// K6: per-block BN2 finalize (from s2g) + out = relu(a2*max + c2)
__global__ __launch_bounds__(256) void apply2(
    const float* __restrict__ maxbuf, const float* __restrict__ s2g,
    const float* __restrict__ g2, const float* __restrict__ b2,
    float* __restrict__ outp){
  __shared__ float a2s[128], c2s[128];
  const int tid = threadIdx.x;
  if (tid < 128){
    const float inv = 1.f/(float)TOT;
    float m = s2g[tid]*inv;
    float v = s2g[128+tid]*inv - m*m;
    float a = g2[tid]*rsqrtf(v + BN_EPS);
    a2s[tid] = a;
    c2s[tid] = fmaf(-m, a, b2[tid]);
  }
  __syncthreads();
  int i = blockIdx.x*256 + tid;                    // 1048576
  int o = i & 127;
  outp[i] = fmaxf(fmaf(maxbuf[i], a2s[o], c2s[o]), 0.f);
}

extern "C" void kernel_launch(void* const* d_in, const int* in_sizes, int n_in,
                              void* d_out, int out_size, void* d_ws, size_t ws_size,
                              hipStream_t stream){
  const float* xyz = (const float*)d_in[0];
  const float* pts = (const float*)d_in[1];
  const float* W0  = (const float*)d_in[2];
  const float* g0  = (const float*)d_in[3];
  const float* b0  = (const float*)d_in[4];
  const float* W1  = (const float*)d_in[5];
  const float* g1  = (const float*)d_in[6];
  const float* b1  = (const float*)d_in[7];
  const float* W2  = (const float*)d_in[8];
  const float* g2  = (const float*)d_in[9];
  const float* b2  = (const float*)d_in[10];
  float* out = (float*)d_out;

  float* ws      = (float*)d_ws;
  f16*   grouped = (f16*)ws;                         // 9*TOT f16 SoA
  f16*   g16     = (f16*)(ws + (size_t)5*TOT);       // 16*TOT f16 [elem][16]
  float* maxbuf  = ws + (size_t)13*TOT;              // 4*TOT
  float4* xyzp   = (float4*)(ws + (size_t)17*TOT);   // 32768 float4
  float* basep   = ws + (size_t)17*TOT + 131072;
  f16*   W0h     = (f16*)basep;                      // 2048 f16
  f16*   W1h     = (f16*)(basep + 1024);             // 4096 f16
  f16*   W2h     = (f16*)(basep + 3072);             // 8192 f16
  float* s0m     = basep + 7168;                     // 160
  float* s1g     = s0m + 160;                        // 128
  float* s2g     = s1g + 128;                        // 256 (contig memset 544)
  float* ac0     = s2g + 256;                        // 128

  (void)hipMemsetAsync(s0m, 0, 544*sizeof(float), stream);
  prep      <<< 128, 256, 0, stream>>>(xyz, xyzp);
  knn_gather<<<1024, 256, 0, stream>>>(xyzp, pts, grouped, g16, out);
  stats0m   <<< 128, 256, 0, stream>>>(grouped, s0m);
  finalize0 <<<   1, 256, 0, stream>>>(s0m, W0, g0, b0, ac0, W1, W2, W0h, W1h, W2h);
  layer1s   <<<1024, 256, 0, stream>>>(g16, W0h, W1h, ac0, s1g);
  layer2max <<<1024, 256, 0, stream>>>(g16, W0h, W1h, W2h, ac0, s1g, g1, b1, maxbuf, s2g);
  apply2    <<<4096, 256, 0, stream>>>(maxbuf, s2g, g2, b2, out + 24576);
}

// Round 11
// 215.333 us; speedup vs baseline: 1.0085x; 1.0085x over previous
//
#include <hip/hip_runtime.h>
#include <float.h>
#include <stdint.h>

// B=8, N=4096, S=1024 queries/batch, K=32 neighbors
#define TOT   262144      // 8*1024*32 grouped elements
#define NPTS  4096
#define KNN   32
#define BN_EPS 1e-5f
#define CAPV  64          // kNN fast-path candidate capacity (1 per lane)

typedef _Float16 f16;
typedef _Float16 f16x2 __attribute__((ext_vector_type(2)));
typedef _Float16 f16x4 __attribute__((ext_vector_type(4)));
typedef _Float16 f16x8 __attribute__((ext_vector_type(8)));
typedef float    f32x4 __attribute__((ext_vector_type(4)));

__device__ __forceinline__ int mbcnt64(unsigned long long m){
  return __builtin_amdgcn_mbcnt_hi((unsigned)(m>>32),
         __builtin_amdgcn_mbcnt_lo((unsigned)(m & 0xffffffffull), 0));
}
__device__ __forceinline__ unsigned f2ord(float f){
  unsigned u = __float_as_uint(f);
  return u ^ (((unsigned)((int)u >> 31)) | 0x80000000u);
}
// packed bn+relu on 2 f16 halves
__device__ __forceinline__ f16x2 bnrelu2(f16x2 x, f16x2 a, f16x2 c){
  f16x2 r = x*a + c;
  const f16 z = (f16)0.f;
  r[0] = r[0] > z ? r[0] : z;
  r[1] = r[1] > z ? r[1] : z;
  return r;
}
// write one gathered element: SoA f16 (for stats gram) + [elem][16] (MFMA B-frags)
__device__ __forceinline__ void writeElem(int n, int e, float qx, float qy, float qz,
    const float4* __restrict__ xb, const float* __restrict__ fb,
    f16* __restrict__ grouped, f16* __restrict__ g16){
  float4 P = xb[n];
  f16 a[16];
  a[0]=(f16)(P.x-qx); a[1]=(f16)(P.y-qy); a[2]=(f16)(P.z-qz);
  #pragma unroll
  for (int c6=0;c6<6;c6++) a[3+c6] = (f16)fb[n*6+c6];
  #pragma unroll
  for (int i=9;i<16;i++) a[i]=(f16)0.f;
  #pragma unroll
  for (int c=0;c<9;c++) grouped[c*TOT+e] = a[c];
  f16x8 lo, hi;
  #pragma unroll
  for (int i=0;i<8;i++){ lo[i]=a[i]; hi[i]=a[8+i]; }
  *(f16x8*)(g16 + (size_t)e*16)     = lo;
  *(f16x8*)(g16 + (size_t)e*16 + 8) = hi;
}

// P0: xyz -> float4 {x,y,z,|p|^2}
__global__ __launch_bounds__(256) void prep(const float* __restrict__ xyz,
    float4* __restrict__ xyzp){
  int p = blockIdx.x*256 + threadIdx.x;            // 32768 points
  float x = xyz[p*3+0], y = xyz[p*3+1], z = xyz[p*3+2];
  xyzp[p] = make_float4(x, y, z, x*x+y*y+z*z);
}

// K1: block = 4 waves = 8 queries (2/wave), grid 1024. Points staged through
// a 16KB LDS tile; distance loop reads LDS not L2. Pass A: per-lane min ->
// joint bitonic -> Uf bound. Pass B: re-stage, LDS-atomic compact d<=Uf.
// Joint u64 bitonic of (f2ord(d),idx) -> exact top-32 (top_k tie order).
__global__ __launch_bounds__(256) void knn_gather(
    const float4* __restrict__ xyzp, const float* __restrict__ pts,
    f16* __restrict__ grouped, f16* __restrict__ g16,
    float* __restrict__ out_newxyz){
  __shared__ float4 tile[1024];
  __shared__ unsigned wk[8][CAPV];
  __shared__ unsigned short wi[8][CAPV];
  __shared__ unsigned lcnt[8];
  const int tid = threadIdx.x, lane = tid & 63, wv = tid >> 6;
  const int q0 = blockIdx.x*8 + wv*2;              // wave's 2 queries
  const int b  = (blockIdx.x*8) >> 10;             // same batch for block
  const float4* xb = xyzp + b*NPTS;
  float qx[2],qy[2],qz[2],qq[2];
  #pragma unroll
  for (int t=0;t<2;t++){
    int s = (q0+t) & 1023;
    float4 Q = xb[s*4];
    qx[t]=Q.x; qy[t]=Q.y; qz[t]=Q.z; qq[t]=Q.w;
  }
  if (tid < 8) lcnt[tid] = 0;
  if (lane == 0){
    #pragma unroll
    for (int t=0;t<2;t++){
      out_newxyz[(q0+t)*3+0]=qx[t]; out_newxyz[(q0+t)*3+1]=qy[t];
      out_newxyz[(q0+t)*3+2]=qz[t];
    }
  }

  // pass A: per-lane min distance over this lane's 64 points (4 tiles x 16)
  float dmin[2] = {FLT_MAX, FLT_MAX};
  #pragma unroll 1
  for (int tl=0; tl<4; ++tl){
    __syncthreads();
    #pragma unroll
    for (int i=0;i<4;i++) tile[i*256+tid] = xb[tl*1024 + i*256 + tid];
    __syncthreads();
    #pragma unroll 4
    for (int i=0;i<16;i++){
      float4 P = tile[i*64+lane];
      #pragma unroll
      for (int t=0;t<2;t++){
        float d = (qq[t]+P.w) - 2.f*(qx[t]*P.x+qy[t]*P.y+qz[t]*P.z);
        dmin[t] = d < dmin[t] ? d : dmin[t];
      }
    }
  }
  // joint float bitonic sort of minima ascending
  float sm[2] = {dmin[0], dmin[1]};
  #pragma unroll
  for (int k=2;k<=64;k<<=1){
    #pragma unroll
    for (int j=k>>1;j>0;j>>=1){
      bool keepmin = (((lane&k)==0) == ((lane&j)==0));
      #pragma unroll
      for (int t=0;t<2;t++){
        float o = __shfl_xor(sm[t], j, 64);
        sm[t] = keepmin ? fminf(sm[t],o) : fmaxf(sm[t],o);
      }
    }
  }
  float Uf[2];
  #pragma unroll
  for (int t=0;t<2;t++) Uf[t] = __shfl(sm[t], 31, 64);

  // pass B: re-stage tiles; compact candidates d<=Uf (order-free)
  #pragma unroll 1
  for (int tl=0; tl<4; ++tl){
    __syncthreads();
    #pragma unroll
    for (int i=0;i<4;i++) tile[i*256+tid] = xb[tl*1024 + i*256 + tid];
    __syncthreads();
    #pragma unroll 2
    for (int i=0;i<16;i++){
      float4 P = tile[i*64+lane];
      #pragma unroll
      for (int t=0;t<2;t++){
        float d = (qq[t]+P.w) - 2.f*(qx[t]*P.x+qy[t]*P.y+qz[t]*P.z);
        if (d <= Uf[t]){
          unsigned p = atomicAdd(&lcnt[wv*2+t], 1u);
          if (p < CAPV){
            wk[wv*2+t][p] = f2ord(d);
            wi[wv*2+t][p] = (unsigned short)(tl*1024 + i*64 + lane);
          }
        }
      }
    }
  }
  int cnt[2] = {(int)lcnt[wv*2], (int)lcnt[wv*2+1]};

  // joint u64 bitonic of (key<<16)|idx
  unsigned long long v[2];
  #pragma unroll
  for (int t=0;t<2;t++){
    unsigned myk = (lane<cnt[t]) ? wk[wv*2+t][lane] : 0xFFFFFFFFu;
    unsigned myi = (lane<cnt[t]) ? wi[wv*2+t][lane] : 0u;
    v[t] = (((unsigned long long)myk)<<16) | myi;
  }
  #pragma unroll
  for (int k=2;k<=64;k<<=1){
    #pragma unroll
    for (int j=k>>1;j>0;j>>=1){
      bool keepmin = (((lane&k)==0) == ((lane&j)==0));
      #pragma unroll
      for (int t=0;t<2;t++){
        unsigned long long o = __shfl_xor(v[t], j, 64);
        v[t] = keepmin ? (v[t]<o?v[t]:o) : (v[t]>o?v[t]:o);
      }
    }
  }

  const float* fb = pts + (size_t)b*NPTS*6;
  #pragma unroll 1
  for (int t=0;t<2;t++){
    const int ebase = (q0+t)*KNN;
    if (cnt[t] <= CAPV){
      if (lane < KNN){
        int n = (int)(v[t] & 0xffffull);
        writeElem(n, ebase+lane, qx[t],qy[t],qz[t], xb, fb, grouped, g16);
      }
    } else {
      // slow exact path (rare): global rescan, radix bisect + ordered collect
      unsigned V=0;
      for (int bit=31; bit>=0; --bit){
        unsigned X = V | (1u<<bit);
        int c=0;
        for (int j=0;j<64;j++){
          float4 P = xb[j*64+lane];
          float d = (qq[t]+P.w) - 2.f*(qx[t]*P.x+qy[t]*P.y+qz[t]*P.z);
          c += __popcll(__ballot(f2ord(d) < X));
        }
        if (c < KNN) V = X;
      }
      int cnt2=0;
      for (int pass=0; pass<2; ++pass){
        for (int j=0;j<64;j++){
          float4 P = xb[j*64+lane];
          float d = (qq[t]+P.w) - 2.f*(qx[t]*P.x+qy[t]*P.y+qz[t]*P.z);
          unsigned kk = f2ord(d);
          bool sel = pass ? (kk==V) : (kk<V);
          unsigned long long msk = __ballot(sel);
          int pos = cnt2 + mbcnt64(msk);
          if (sel && pos < KNN)
            writeElem(j*64+lane, ebase+pos, qx[t],qy[t],qz[t], xb, fb, grouped, g16);
          cnt2 += __popcll(msk);
        }
      }
    }
  }
}

// K2: second-moment matrix via MFMA gram. G' = [g(9ch), 1]; M = G'^T G'.
// Coverage: 128 blocks x 4 waves x 16 chunks x 32 elems = 262144 = TOT.
__global__ __launch_bounds__(256) void stats0m(const f16* __restrict__ grouped,
    float* __restrict__ s0m){
  const int lane = threadIdx.x & 63, wv = threadIdx.x >> 6;
  const int c = lane & 15, q = lane >> 4;
  const int base = (blockIdx.x*4 + wv)*512;        // 512 elems per wave
  f16x8 cfill = {};
  if (c == 9){
    #pragma unroll
    for (int i=0;i<8;i++) cfill[i] = (f16)1.f;
  }
  f32x4 acc = {0.f,0.f,0.f,0.f};
  #pragma unroll 4
  for (int chunk=0; chunk<16; ++chunk){
    int e = base + chunk*32 + q*8;
    f16x8 f = cfill;
    if (c < 9) f = *(const f16x8*)(grouped + (size_t)c*TOT + e);
    acc = __builtin_amdgcn_mfma_f32_16x16x32_f16(f, f, acc, 0,0,0);
  }
  __shared__ float red[4][16][16];
  #pragma unroll
  for (int i=0;i<4;i++) red[wv][q*4+i][c] = acc[i];
  __syncthreads();
  const int tid = threadIdx.x;
  if (tid < 160){
    int row = tid>>4, col = tid&15;
    float vv = red[0][row][col]+red[1][row][col]+red[2][row][col]+red[3][row][col];
    atomicAdd(&s0m[tid], vv);
  }
}

// K3: M(10x16) -> BN0 coeffs; W0h = a0-folded W0 (f16 [64][32] K-pad); W1h/W2h f16
__global__ void finalize0(const float* __restrict__ s0m,
    const float* __restrict__ W0, const float* __restrict__ g0,
    const float* __restrict__ b0, float* __restrict__ ac0,
    const float* __restrict__ W1, const float* __restrict__ W2,
    f16* __restrict__ W0h, f16* __restrict__ W1h, f16* __restrict__ W2h){
  const int tid = threadIdx.x;                     // 256
  __shared__ float S[160];
  __shared__ float A0s[64];
  if (tid < 160) S[tid] = s0m[tid];
  __syncthreads();
  if (tid < 64){
    float w[9];
    #pragma unroll
    for (int c=0;c<9;c++) w[c]=W0[tid*9+c];
    const float inv = 1.f/(float)TOT;
    float m=0.f;
    #pragma unroll
    for (int c=0;c<9;c++) m = fmaf(w[c], S[c*16+9], m);
    m *= inv;
    float e2=0.f;
    #pragma unroll
    for (int c1=0;c1<9;c1++){
      float t=0.f;
      #pragma unroll
      for (int c2=0;c2<9;c2++) t = fmaf(w[c2], S[c1*16+c2], t);
      e2 = fmaf(w[c1], t, e2);
    }
    e2 *= inv;
    float var = e2 - m*m;
    float a = g0[tid]*rsqrtf(var + BN_EPS);
    ac0[tid]    = a;
    ac0[64+tid] = fmaf(-m, a, b0[tid]);
    A0s[tid]    = a;
  }
  __syncthreads();
  for (int i=tid; i<2048; i+=256){
    int o = i>>5, c = i&31;
    W0h[i] = (f16)(c<9 ? A0s[o]*W0[o*9+c] : 0.f);
  }
  for (int i=tid; i<4096; i+=256) W1h[i] = (f16)W1[i];
  for (int i=tid; i<8192; i+=256) W2h[i] = (f16)W2[i];
}

// K4: BN1-stats only, grid 1024 (4 subs/wave). Weights staged in LDS.
// launch_bounds(256,2): VGPR budget 256 -> no scratch spill.
__global__ __launch_bounds__(256, 2) void layer1s(
    const f16* __restrict__ g16, const f16* __restrict__ W0h,
    const f16* __restrict__ W1h, const float* __restrict__ ac0,
    float* __restrict__ s1g){
  __shared__ f16 sW0[2048];
  __shared__ f16 sW1[4096];
  __shared__ float ac0c[64];
  __shared__ f16 hb0[4][16][72];
  __shared__ float sred[4][128];
  const int tid = threadIdx.x;
  const int lane = tid & 63, wv = tid >> 6;
  const int e16 = lane & 15, q = lane >> 4;
  *(f16x8*)(&sW0[tid*8]) = *(const f16x8*)(W0h + tid*8);
  *(f16x8*)(&sW1[tid*8])        = *(const f16x8*)(W1h + tid*8);
  *(f16x8*)(&sW1[2048 + tid*8]) = *(const f16x8*)(W1h + 2048 + tid*8);
  if (tid < 64) ac0c[tid] = ac0[64+tid];
  __syncthreads();

  const int base = blockIdx.x*256 + wv*64;         // grid 1024
  float ssum[16], ssq[16];
  #pragma unroll
  for (int i=0;i<16;i++){ ssum[i]=0.f; ssq[i]=0.f; }

  #pragma unroll 1
  for (int sub=0; sub<4; ++sub){
    int elem = base + sub*16 + e16;
    f16x8 bg = {};
    if (q < 2) bg = *(const f16x8*)(g16 + (size_t)elem*16 + q*8);
    #pragma unroll
    for (int m=0;m<4;m++){
      f32x4 acc = *(const f32x4*)(&ac0c[m*16 + q*4]);
      f16x8 A0f = *(const f16x8*)(&sW0[(m*16+e16)*32 + q*8]);
      acc = __builtin_amdgcn_mfma_f32_16x16x32_f16(A0f, bg, acc, 0,0,0);
      f16x4 w;
      w[0]=(f16)fmaxf(acc[0],0.f); w[1]=(f16)fmaxf(acc[1],0.f);
      w[2]=(f16)fmaxf(acc[2],0.f); w[3]=(f16)fmaxf(acc[3],0.f);
      *(f16x4*)(&hb0[wv][e16][m*16 + q*4]) = w;
    }
    f32x4 acc2[4];
    #pragma unroll
    for (int m=0;m<4;m++) acc2[m] = (f32x4){0.f,0.f,0.f,0.f};
    #pragma unroll
    for (int s=0;s<2;s++){
      f16x8 bh = *(const f16x8*)(&hb0[wv][e16][s*32 + q*8]);
      #pragma unroll
      for (int m=0;m<4;m++){
        f16x8 A1f = *(const f16x8*)(&sW1[(m*16+e16)*64 + s*32 + q*8]);
        acc2[m] = __builtin_amdgcn_mfma_f32_16x16x32_f16(A1f, bh, acc2[m], 0,0,0);
      }
    }
    #pragma unroll
    for (int m=0;m<4;m++)
      #pragma unroll
      for (int i=0;i<4;i++){
        float x = acc2[m][i];
        ssum[m*4+i] += x;
        ssq[m*4+i]  = fmaf(x, x, ssq[m*4+i]);
      }
  }
  #pragma unroll
  for (int t=0;t<16;t++){
    float a = ssum[t], bq = ssq[t];
    #pragma unroll
    for (int off=1; off<16; off<<=1){
      a  += __shfl_xor(a,  off, 64);
      bq += __shfl_xor(bq, off, 64);
    }
    ssum[t]=a; ssq[t]=bq;
  }
  if (e16==0){
    #pragma unroll
    for (int m=0;m<4;m++)
      #pragma unroll
      for (int i=0;i<4;i++){
        int ch = m*16 + q*4 + i;
        sred[wv][ch]    = ssum[m*4+i];
        sred[wv][64+ch] = ssq[m*4+i];
      }
  }
  __syncthreads();
  if (tid < 128){
    float v = sred[0][tid]+sred[1][tid]+sred[2][tid]+sred[3][tid];
    atomicAdd(&s1g[tid], v);
  }
}

// K5: recompute x1 (weights from LDS), BN1+relu, GEMM3 vs W2 in 2 nt-groups.
// launch_bounds(256,2): VGPR budget 256 -> Bw+acc3 stay in regs (no spill).
// Final-reduction buffer overlays dead hb0 -> LDS 40.4 KB (4 blocks/CU).
__global__ __launch_bounds__(256, 2) void layer2max(
    const f16* __restrict__ g16, const f16* __restrict__ W0h,
    const f16* __restrict__ W1h, const f16* __restrict__ W2h,
    const float* __restrict__ ac0, const float* __restrict__ s1g,
    const float* __restrict__ g1, const float* __restrict__ b1,
    float* __restrict__ maxbuf, float* __restrict__ s2g){
  __shared__ f16 sW0[2048];
  __shared__ f16 sW1[4096];
  __shared__ float ac0c[64];
  __shared__ f16 ac1s[128];
  __shared__ f16 hb0[4][16][72];
  __shared__ f16 hb1[4][2][16][72];
  float (*redbuf)[256] = (float(*)[256])hb0;       // overlay (hb0 dead by then)
  const int tid = threadIdx.x;
  const int lane = tid & 63, wv = tid >> 6;
  const int e16 = lane & 15, q = lane >> 4;
  *(f16x8*)(&sW0[tid*8]) = *(const f16x8*)(W0h + tid*8);
  *(f16x8*)(&sW1[tid*8])        = *(const f16x8*)(W1h + tid*8);
  *(f16x8*)(&sW1[2048 + tid*8]) = *(const f16x8*)(W1h + 2048 + tid*8);
  if (tid < 64) ac0c[tid] = ac0[64+tid];
  if (tid < 64){
    const float inv = 1.f/(float)TOT;
    float m = s1g[tid]*inv;
    float vv = s1g[64+tid]*inv - m*m;
    float a = g1[tid]*rsqrtf(vv + BN_EPS);
    ac1s[tid]    = (f16)a;
    ac1s[64+tid] = (f16)fmaf(-m, a, b1[tid]);
  }
  __syncthreads();

  f16x8 Bw[8][2];                                  // W2 frags, persistent
  #pragma unroll
  for (int nt=0;nt<8;nt++)
    #pragma unroll
    for (int s=0;s<2;s++) Bw[nt][s] = *(const f16x8*)(W2h + (nt*16+e16)*64 + s*32 + q*8);

  float ssum[8], ssq[8];
  #pragma unroll
  for (int i=0;i<8;i++){ ssum[i]=0.f; ssq[i]=0.f; }

  #pragma unroll 1
  for (int qq=0; qq<2; ++qq){                      // 2 queries per wave
    const int qid = blockIdx.x*8 + wv*2 + qq;
    // phase 1: h1 tiles for mt=0,1 into hb1
    #pragma unroll 1
    for (int mt=0; mt<2; ++mt){
      int elem = qid*32 + mt*16 + e16;
      f16x8 bg = {};
      if (q < 2) bg = *(const f16x8*)(g16 + (size_t)elem*16 + q*8);
      #pragma unroll
      for (int m=0;m<4;m++){
        f32x4 acc = *(const f32x4*)(&ac0c[m*16 + q*4]);
        f16x8 A0f = *(const f16x8*)(&sW0[(m*16+e16)*32 + q*8]);
        acc = __builtin_amdgcn_mfma_f32_16x16x32_f16(A0f, bg, acc, 0,0,0);
        f16x4 w;
        w[0]=(f16)fmaxf(acc[0],0.f); w[1]=(f16)fmaxf(acc[1],0.f);
        w[2]=(f16)fmaxf(acc[2],0.f); w[3]=(f16)fmaxf(acc[3],0.f);
        *(f16x4*)(&hb0[wv][e16][m*16 + q*4]) = w;
      }
      f32x4 acc2[4];
      #pragma unroll
      for (int m=0;m<4;m++) acc2[m] = (f32x4){0.f,0.f,0.f,0.f};
      #pragma unroll
      for (int s=0;s<2;s++){
        f16x8 bh = *(const f16x8*)(&hb0[wv][e16][s*32 + q*8]);
        #pragma unroll
        for (int m=0;m<4;m++){
          f16x8 A1f = *(const f16x8*)(&sW1[(m*16+e16)*64 + s*32 + q*8]);
          acc2[m] = __builtin_amdgcn_mfma_f32_16x16x32_f16(A1f, bh, acc2[m], 0,0,0);
        }
      }
      #pragma unroll
      for (int m=0;m<4;m++){
        f16x4 a4 = *(const f16x4*)(&ac1s[m*16 + q*4]);
        f16x4 c4 = *(const f16x4*)(&ac1s[64 + m*16 + q*4]);
        f16x2 p0 = bnrelu2((f16x2){(f16)acc2[m][0], (f16)acc2[m][1]},
                           (f16x2){a4[0],a4[1]}, (f16x2){c4[0],c4[1]});
        f16x2 p1 = bnrelu2((f16x2){(f16)acc2[m][2], (f16)acc2[m][3]},
                           (f16x2){a4[2],a4[3]}, (f16x2){c4[2],c4[3]});
        f16x4 w; w[0]=p0[0]; w[1]=p0[1]; w[2]=p1[0]; w[3]=p1[1];
        *(f16x4*)(&hb1[wv][mt][e16][m*16 + q*4]) = w;
      }
    }
    // phase 2: GEMM3, nt in 2 groups of 4 (acc3 = 32 VGPR live)
    float mx[8];
    #pragma unroll 1
    for (int g=0; g<2; ++g){
      f32x4 acc3[4][2];
      #pragma unroll
      for (int j=0;j<4;j++){ acc3[j][0]=(f32x4){0,0,0,0}; acc3[j][1]=(f32x4){0,0,0,0}; }
      #pragma unroll
      for (int mt=0; mt<2; ++mt)
        #pragma unroll
        for (int s=0;s<2;s++){
          f16x8 af = *(const f16x8*)(&hb1[wv][mt][e16][s*32 + q*8]);
          #pragma unroll
          for (int j=0;j<4;j++)
            acc3[j][mt] = __builtin_amdgcn_mfma_f32_16x16x32_f16(af, Bw[g*4+j][s], acc3[j][mt], 0,0,0);
        }
      #pragma unroll
      for (int j=0;j<4;j++){
        int nt = g*4 + j;
        f32x4 u = acc3[j][0], vv = acc3[j][1];
        float m1 = fmaxf(fmaxf(u[0],u[1]), fmaxf(u[2],u[3]));
        float m2 = fmaxf(fmaxf(vv[0],vv[1]), fmaxf(vv[2],vv[3]));
        float m = fmaxf(m1, m2);
        ssum[nt] += (u[0]+u[1])+(u[2]+u[3]) + (vv[0]+vv[1])+(vv[2]+vv[3]);
        float sq = 0.f;
        #pragma unroll
        for (int i=0;i<4;i++){ sq = fmaf(u[i],u[i],sq); sq = fmaf(vv[i],vv[i],sq); }
        ssq[nt] += sq;
        m = fmaxf(m, __shfl_xor(m, 16, 64));
        m = fmaxf(m, __shfl_xor(m, 32, 64));
        mx[nt] = m;
      }
    }
    if (lane < 16){
      #pragma unroll
      for (int nt=0;nt<8;nt++) maxbuf[(size_t)qid*128 + nt*16 + lane] = mx[nt];
    }
  }
  #pragma unroll
  for (int nt=0;nt<8;nt++){
    ssum[nt] += __shfl_xor(ssum[nt], 16, 64);
    ssum[nt] += __shfl_xor(ssum[nt], 32, 64);
    ssq[nt]  += __shfl_xor(ssq[nt], 16, 64);
    ssq[nt]  += __shfl_xor(ssq[nt], 32, 64);
  }
  __syncthreads();                                 // all hb0 reads done before overlay
  if (q==0){
    #pragma unroll
    for (int nt=0;nt<8;nt++){
      redbuf[wv][nt*16+e16]     = ssum[nt];
      redbuf[wv][128+nt*16+e16] = ssq[nt];
    }
  }
  __syncthreads();
  float v = redbuf[0][tid]+redbuf[1][tid]+redbuf[2][tid]+redbuf[3][tid];
  atomicAdd(&s2g[tid], v);
}

// K6: per-block BN2 finalize (from s2g) + out = relu(a2*max + c2)
__global__ __launch_bounds__(256) void apply2(
    const float* __restrict__ maxbuf, const float* __restrict__ s2g,
    const float* __restrict__ g2, const float* __restrict__ b2,
    float* __restrict__ outp){
  __shared__ float a2s[128], c2s[128];
  const int tid = threadIdx.x;
  if (tid < 128){
    const float inv = 1.f/(float)TOT;
    float m = s2g[tid]*inv;
    float v = s2g[128+tid]*inv - m*m;
    float a = g2[tid]*rsqrtf(v + BN_EPS);
    a2s[tid] = a;
    c2s[tid] = fmaf(-m, a, b2[tid]);
  }
  __syncthreads();
  int i = blockIdx.x*256 + tid;                    // 1048576
  int o = i & 127;
  outp[i] = fmaxf(fmaf(maxbuf[i], a2s[o], c2s[o]), 0.f);
}

extern "C" void kernel_launch(void* const* d_in, const int* in_sizes, int n_in,
                              void* d_out, int out_size, void* d_ws, size_t ws_size,
                              hipStream_t stream){
  const float* xyz = (const float*)d_in[0];
  const float* pts = (const float*)d_in[1];
  const float* W0  = (const float*)d_in[2];
  const float* g0  = (const float*)d_in[3];
  const float* b0  = (const float*)d_in[4];
  const float* W1  = (const float*)d_in[5];
  const float* g1  = (const float*)d_in[6];
  const float* b1  = (const float*)d_in[7];
  const float* W2  = (const float*)d_in[8];
  const float* g2  = (const float*)d_in[9];
  const float* b2  = (const float*)d_in[10];
  float* out = (float*)d_out;

  float* ws      = (float*)d_ws;
  f16*   grouped = (f16*)ws;                         // 9*TOT f16 SoA
  f16*   g16     = (f16*)(ws + (size_t)5*TOT);       // 16*TOT f16 [elem][16]
  float* maxbuf  = ws + (size_t)13*TOT;              // 4*TOT
  float4* xyzp   = (float4*)(ws + (size_t)17*TOT);   // 32768 float4
  float* basep   = ws + (size_t)17*TOT + 131072;
  f16*   W0h     = (f16*)basep;                      // 2048 f16
  f16*   W1h     = (f16*)(basep + 1024);             // 4096 f16
  f16*   W2h     = (f16*)(basep + 3072);             // 8192 f16
  float* s0m     = basep + 7168;                     // 160
  float* s1g     = s0m + 160;                        // 128
  float* s2g     = s1g + 128;                        // 256 (contig memset 544)
  float* ac0     = s2g + 256;                        // 128

  (void)hipMemsetAsync(s0m, 0, 544*sizeof(float), stream);
  prep      <<< 128, 256, 0, stream>>>(xyz, xyzp);
  knn_gather<<<1024, 256, 0, stream>>>(xyzp, pts, grouped, g16, out);
  stats0m   <<< 128, 256, 0, stream>>>(grouped, s0m);
  finalize0 <<<   1, 256, 0, stream>>>(s0m, W0, g0, b0, ac0, W1, W2, W0h, W1h, W2h);
  layer1s   <<<1024, 256, 0, stream>>>(g16, W0h, W1h, ac0, s1g);
  layer2max <<<1024, 256, 0, stream>>>(g16, W0h, W1h, W2h, ac0, s1g, g1, b1, maxbuf, s2g);
  apply2    <<<4096, 256, 0, stream>>>(maxbuf, s2g, g2, b2, out + 24576);
}

// Round 12
// 203.113 us; speedup vs baseline: 1.0691x; 1.0602x over previous
//
#include <hip/hip_runtime.h>
#include <float.h>
#include <stdint.h>

// B=8, N=4096, S=1024 queries/batch, K=32 neighbors
#define TOT   262144      // 8*1024*32 grouped elements
#define NPTS  4096
#define KNN   32
#define BN_EPS 1e-5f
#define CAPV  64          // kNN fast-path candidate capacity (1 per lane)

typedef _Float16 f16;
typedef _Float16 f16x2 __attribute__((ext_vector_type(2)));
typedef _Float16 f16x4 __attribute__((ext_vector_type(4)));
typedef _Float16 f16x8 __attribute__((ext_vector_type(8)));
typedef float    f32x4 __attribute__((ext_vector_type(4)));

__device__ __forceinline__ int mbcnt64(unsigned long long m){
  return __builtin_amdgcn_mbcnt_hi((unsigned)(m>>32),
         __builtin_amdgcn_mbcnt_lo((unsigned)(m & 0xffffffffull), 0));
}
__device__ __forceinline__ unsigned f2ord(float f){
  unsigned u = __float_as_uint(f);
  return u ^ (((unsigned)((int)u >> 31)) | 0x80000000u);
}
// packed bn+relu on 2 f16 halves
__device__ __forceinline__ f16x2 bnrelu2(f16x2 x, f16x2 a, f16x2 c){
  f16x2 r = x*a + c;
  const f16 z = (f16)0.f;
  r[0] = r[0] > z ? r[0] : z;
  r[1] = r[1] > z ? r[1] : z;
  return r;
}
// write one gathered element: SoA f16 (for stats gram) + [elem][16] (MFMA B-frags)
__device__ __forceinline__ void writeElem(int n, int e, float qx, float qy, float qz,
    const float4* __restrict__ xb, const float* __restrict__ fb,
    f16* __restrict__ grouped, f16* __restrict__ g16){
  float4 P = xb[n];
  f16 a[16];
  a[0]=(f16)(P.x-qx); a[1]=(f16)(P.y-qy); a[2]=(f16)(P.z-qz);
  #pragma unroll
  for (int c6=0;c6<6;c6++) a[3+c6] = (f16)fb[n*6+c6];
  #pragma unroll
  for (int i=9;i<16;i++) a[i]=(f16)0.f;
  #pragma unroll
  for (int c=0;c<9;c++) grouped[c*TOT+e] = a[c];
  f16x8 lo, hi;
  #pragma unroll
  for (int i=0;i<8;i++){ lo[i]=a[i]; hi[i]=a[8+i]; }
  *(f16x8*)(g16 + (size_t)e*16)     = lo;
  *(f16x8*)(g16 + (size_t)e*16 + 8) = hi;
}

// P0: xyz -> float4 {x,y,z,|p|^2}
__global__ __launch_bounds__(256) void prep(const float* __restrict__ xyz,
    float4* __restrict__ xyzp){
  int p = blockIdx.x*256 + threadIdx.x;            // 32768 points
  float x = xyz[p*3+0], y = xyz[p*3+1], z = xyz[p*3+2];
  xyzp[p] = make_float4(x, y, z, x*x+y*y+z*z);
}

// K1: block = 4 waves = 8 queries (2/wave), grid 1024. Points staged through
// a 16KB LDS tile; distance loop reads LDS not L2. Pass A: per-lane min ->
// joint bitonic -> Uf bound. Pass B: re-stage, LDS-atomic compact d<=Uf.
// Joint u64 bitonic of (f2ord(d),idx) -> exact top-32 (top_k tie order).
__global__ __launch_bounds__(256) void knn_gather(
    const float4* __restrict__ xyzp, const float* __restrict__ pts,
    f16* __restrict__ grouped, f16* __restrict__ g16,
    float* __restrict__ out_newxyz){
  __shared__ float4 tile[1024];
  __shared__ unsigned wk[8][CAPV];
  __shared__ unsigned short wi[8][CAPV];
  __shared__ unsigned lcnt[8];
  const int tid = threadIdx.x, lane = tid & 63, wv = tid >> 6;
  const int q0 = blockIdx.x*8 + wv*2;              // wave's 2 queries
  const int b  = (blockIdx.x*8) >> 10;             // same batch for block
  const float4* xb = xyzp + b*NPTS;
  float qx[2],qy[2],qz[2],qq[2];
  #pragma unroll
  for (int t=0;t<2;t++){
    int s = (q0+t) & 1023;
    float4 Q = xb[s*4];
    qx[t]=Q.x; qy[t]=Q.y; qz[t]=Q.z; qq[t]=Q.w;
  }
  if (tid < 8) lcnt[tid] = 0;
  if (lane == 0){
    #pragma unroll
    for (int t=0;t<2;t++){
      out_newxyz[(q0+t)*3+0]=qx[t]; out_newxyz[(q0+t)*3+1]=qy[t];
      out_newxyz[(q0+t)*3+2]=qz[t];
    }
  }

  // pass A: per-lane min distance over this lane's 64 points (4 tiles x 16)
  float dmin[2] = {FLT_MAX, FLT_MAX};
  #pragma unroll 1
  for (int tl=0; tl<4; ++tl){
    __syncthreads();
    #pragma unroll
    for (int i=0;i<4;i++) tile[i*256+tid] = xb[tl*1024 + i*256 + tid];
    __syncthreads();
    #pragma unroll 4
    for (int i=0;i<16;i++){
      float4 P = tile[i*64+lane];
      #pragma unroll
      for (int t=0;t<2;t++){
        float d = (qq[t]+P.w) - 2.f*(qx[t]*P.x+qy[t]*P.y+qz[t]*P.z);
        dmin[t] = d < dmin[t] ? d : dmin[t];
      }
    }
  }
  // joint float bitonic sort of minima ascending
  float sm[2] = {dmin[0], dmin[1]};
  #pragma unroll
  for (int k=2;k<=64;k<<=1){
    #pragma unroll
    for (int j=k>>1;j>0;j>>=1){
      bool keepmin = (((lane&k)==0) == ((lane&j)==0));
      #pragma unroll
      for (int t=0;t<2;t++){
        float o = __shfl_xor(sm[t], j, 64);
        sm[t] = keepmin ? fminf(sm[t],o) : fmaxf(sm[t],o);
      }
    }
  }
  float Uf[2];
  #pragma unroll
  for (int t=0;t<2;t++) Uf[t] = __shfl(sm[t], 31, 64);

  // pass B: re-stage tiles; compact candidates d<=Uf (order-free)
  #pragma unroll 1
  for (int tl=0; tl<4; ++tl){
    __syncthreads();
    #pragma unroll
    for (int i=0;i<4;i++) tile[i*256+tid] = xb[tl*1024 + i*256 + tid];
    __syncthreads();
    #pragma unroll 2
    for (int i=0;i<16;i++){
      float4 P = tile[i*64+lane];
      #pragma unroll
      for (int t=0;t<2;t++){
        float d = (qq[t]+P.w) - 2.f*(qx[t]*P.x+qy[t]*P.y+qz[t]*P.z);
        if (d <= Uf[t]){
          unsigned p = atomicAdd(&lcnt[wv*2+t], 1u);
          if (p < CAPV){
            wk[wv*2+t][p] = f2ord(d);
            wi[wv*2+t][p] = (unsigned short)(tl*1024 + i*64 + lane);
          }
        }
      }
    }
  }
  int cnt[2] = {(int)lcnt[wv*2], (int)lcnt[wv*2+1]};

  // joint u64 bitonic of (key<<16)|idx
  unsigned long long v[2];
  #pragma unroll
  for (int t=0;t<2;t++){
    unsigned myk = (lane<cnt[t]) ? wk[wv*2+t][lane] : 0xFFFFFFFFu;
    unsigned myi = (lane<cnt[t]) ? wi[wv*2+t][lane] : 0u;
    v[t] = (((unsigned long long)myk)<<16) | myi;
  }
  #pragma unroll
  for (int k=2;k<=64;k<<=1){
    #pragma unroll
    for (int j=k>>1;j>0;j>>=1){
      bool keepmin = (((lane&k)==0) == ((lane&j)==0));
      #pragma unroll
      for (int t=0;t<2;t++){
        unsigned long long o = __shfl_xor(v[t], j, 64);
        v[t] = keepmin ? (v[t]<o?v[t]:o) : (v[t]>o?v[t]:o);
      }
    }
  }

  const float* fb = pts + (size_t)b*NPTS*6;
  #pragma unroll 1
  for (int t=0;t<2;t++){
    const int ebase = (q0+t)*KNN;
    if (cnt[t] <= CAPV){
      if (lane < KNN){
        int n = (int)(v[t] & 0xffffull);
        writeElem(n, ebase+lane, qx[t],qy[t],qz[t], xb, fb, grouped, g16);
      }
    } else {
      // slow exact path (rare): global rescan, radix bisect + ordered collect
      unsigned V=0;
      for (int bit=31; bit>=0; --bit){
        unsigned X = V | (1u<<bit);
        int c=0;
        for (int j=0;j<64;j++){
          float4 P = xb[j*64+lane];
          float d = (qq[t]+P.w) - 2.f*(qx[t]*P.x+qy[t]*P.y+qz[t]*P.z);
          c += __popcll(__ballot(f2ord(d) < X));
        }
        if (c < KNN) V = X;
      }
      int cnt2=0;
      for (int pass=0; pass<2; ++pass){
        for (int j=0;j<64;j++){
          float4 P = xb[j*64+lane];
          float d = (qq[t]+P.w) - 2.f*(qx[t]*P.x+qy[t]*P.y+qz[t]*P.z);
          unsigned kk = f2ord(d);
          bool sel = pass ? (kk==V) : (kk<V);
          unsigned long long msk = __ballot(sel);
          int pos = cnt2 + mbcnt64(msk);
          if (sel && pos < KNN)
            writeElem(j*64+lane, ebase+pos, qx[t],qy[t],qz[t], xb, fb, grouped, g16);
          cnt2 += __popcll(msk);
        }
      }
    }
  }
}

// K2: second-moment matrix via MFMA gram. G' = [g(9ch), 1]; M = G'^T G'.
// Coverage: 128 blocks x 4 waves x 16 chunks x 32 elems = 262144 = TOT.
__global__ __launch_bounds__(256) void stats0m(const f16* __restrict__ grouped,
    float* __restrict__ s0m){
  const int lane = threadIdx.x & 63, wv = threadIdx.x >> 6;
  const int c = lane & 15, q = lane >> 4;
  const int base = (blockIdx.x*4 + wv)*512;        // 512 elems per wave
  f16x8 cfill = {};
  if (c == 9){
    #pragma unroll
    for (int i=0;i<8;i++) cfill[i] = (f16)1.f;
  }
  f32x4 acc = {0.f,0.f,0.f,0.f};
  #pragma unroll 4
  for (int chunk=0; chunk<16; ++chunk){
    int e = base + chunk*32 + q*8;
    f16x8 f = cfill;
    if (c < 9) f = *(const f16x8*)(grouped + (size_t)c*TOT + e);
    acc = __builtin_amdgcn_mfma_f32_16x16x32_f16(f, f, acc, 0,0,0);
  }
  __shared__ float red[4][16][16];
  #pragma unroll
  for (int i=0;i<4;i++) red[wv][q*4+i][c] = acc[i];
  __syncthreads();
  const int tid = threadIdx.x;
  if (tid < 160){
    int row = tid>>4, col = tid&15;
    float vv = red[0][row][col]+red[1][row][col]+red[2][row][col]+red[3][row][col];
    atomicAdd(&s0m[tid], vv);
  }
}

// K3: M(10x16) -> BN0 coeffs; W0h = a0-folded W0 (f16 [64][32] K-pad); W1h/W2h f16
__global__ void finalize0(const float* __restrict__ s0m,
    const float* __restrict__ W0, const float* __restrict__ g0,
    const float* __restrict__ b0, float* __restrict__ ac0,
    const float* __restrict__ W1, const float* __restrict__ W2,
    f16* __restrict__ W0h, f16* __restrict__ W1h, f16* __restrict__ W2h){
  const int tid = threadIdx.x;                     // 256
  __shared__ float S[160];
  __shared__ float A0s[64];
  if (tid < 160) S[tid] = s0m[tid];
  __syncthreads();
  if (tid < 64){
    float w[9];
    #pragma unroll
    for (int c=0;c<9;c++) w[c]=W0[tid*9+c];
    const float inv = 1.f/(float)TOT;
    float m=0.f;
    #pragma unroll
    for (int c=0;c<9;c++) m = fmaf(w[c], S[c*16+9], m);
    m *= inv;
    float e2=0.f;
    #pragma unroll
    for (int c1=0;c1<9;c1++){
      float t=0.f;
      #pragma unroll
      for (int c2=0;c2<9;c2++) t = fmaf(w[c2], S[c1*16+c2], t);
      e2 = fmaf(w[c1], t, e2);
    }
    e2 *= inv;
    float var = e2 - m*m;
    float a = g0[tid]*rsqrtf(var + BN_EPS);
    ac0[tid]    = a;
    ac0[64+tid] = fmaf(-m, a, b0[tid]);
    A0s[tid]    = a;
  }
  __syncthreads();
  for (int i=tid; i<2048; i+=256){
    int o = i>>5, c = i&31;
    W0h[i] = (f16)(c<9 ? A0s[o]*W0[o*9+c] : 0.f);
  }
  for (int i=tid; i<4096; i+=256) W1h[i] = (f16)W1[i];
  for (int i=tid; i<8192; i+=256) W2h[i] = (f16)W2[i];
}

// K4: BN1-stats only, grid 1024 (4 subs/wave). Weights staged in LDS.
__global__ __launch_bounds__(256, 2) void layer1s(
    const f16* __restrict__ g16, const f16* __restrict__ W0h,
    const f16* __restrict__ W1h, const float* __restrict__ ac0,
    float* __restrict__ s1g){
  __shared__ f16 sW0[2048];
  __shared__ f16 sW1[4096];
  __shared__ float ac0c[64];
  __shared__ f16 hb0[4][16][72];
  __shared__ float sred[4][128];
  const int tid = threadIdx.x;
  const int lane = tid & 63, wv = tid >> 6;
  const int e16 = lane & 15, q = lane >> 4;
  *(f16x8*)(&sW0[tid*8]) = *(const f16x8*)(W0h + tid*8);
  *(f16x8*)(&sW1[tid*8])        = *(const f16x8*)(W1h + tid*8);
  *(f16x8*)(&sW1[2048 + tid*8]) = *(const f16x8*)(W1h + 2048 + tid*8);
  if (tid < 64) ac0c[tid] = ac0[64+tid];
  __syncthreads();

  const int base = blockIdx.x*256 + wv*64;         // grid 1024
  float ssum[16], ssq[16];
  #pragma unroll
  for (int i=0;i<16;i++){ ssum[i]=0.f; ssq[i]=0.f; }

  #pragma unroll 1
  for (int sub=0; sub<4; ++sub){
    int elem = base + sub*16 + e16;
    f16x8 bg = {};
    if (q < 2) bg = *(const f16x8*)(g16 + (size_t)elem*16 + q*8);
    #pragma unroll
    for (int m=0;m<4;m++){
      f32x4 acc = *(const f32x4*)(&ac0c[m*16 + q*4]);
      f16x8 A0f = *(const f16x8*)(&sW0[(m*16+e16)*32 + q*8]);
      acc = __builtin_amdgcn_mfma_f32_16x16x32_f16(A0f, bg, acc, 0,0,0);
      f16x4 w;
      w[0]=(f16)fmaxf(acc[0],0.f); w[1]=(f16)fmaxf(acc[1],0.f);
      w[2]=(f16)fmaxf(acc[2],0.f); w[3]=(f16)fmaxf(acc[3],0.f);
      *(f16x4*)(&hb0[wv][e16][m*16 + q*4]) = w;
    }
    f32x4 acc2[4];
    #pragma unroll
    for (int m=0;m<4;m++) acc2[m] = (f32x4){0.f,0.f,0.f,0.f};
    #pragma unroll
    for (int s=0;s<2;s++){
      f16x8 bh = *(const f16x8*)(&hb0[wv][e16][s*32 + q*8]);
      #pragma unroll
      for (int m=0;m<4;m++){
        f16x8 A1f = *(const f16x8*)(&sW1[(m*16+e16)*64 + s*32 + q*8]);
        acc2[m] = __builtin_amdgcn_mfma_f32_16x16x32_f16(A1f, bh, acc2[m], 0,0,0);
      }
    }
    #pragma unroll
    for (int m=0;m<4;m++)
      #pragma unroll
      for (int i=0;i<4;i++){
        float x = acc2[m][i];
        ssum[m*4+i] += x;
        ssq[m*4+i]  = fmaf(x, x, ssq[m*4+i]);
      }
  }
  #pragma unroll
  for (int t=0;t<16;t++){
    float a = ssum[t], bq = ssq[t];
    #pragma unroll
    for (int off=1; off<16; off<<=1){
      a  += __shfl_xor(a,  off, 64);
      bq += __shfl_xor(bq, off, 64);
    }
    ssum[t]=a; ssq[t]=bq;
  }
  if (e16==0){
    #pragma unroll
    for (int m=0;m<4;m++)
      #pragma unroll
      for (int i=0;i<4;i++){
        int ch = m*16 + q*4 + i;
        sred[wv][ch]    = ssum[m*4+i];
        sred[wv][64+ch] = ssq[m*4+i];
      }
  }
  __syncthreads();
  if (tid < 128){
    float v = sred[0][tid]+sred[1][tid]+sred[2][tid]+sred[3][tid];
    atomicAdd(&s1g[tid], v);
  }
}

// K5: recompute x1 (weights from LDS), BN1+relu, GEMM3 vs W2. Phase-2 nt-group
// loop now FULLY UNROLLED: all Bw/ssum/ssq/mx indices are compile-time
// constants -> arrays stay in registers (dynamic index was forcing scratch:
// 16KB/wave x 4096 waves = 64MB spill traffic in R8-R11).
__global__ __launch_bounds__(256, 2) void layer2max(
    const f16* __restrict__ g16, const f16* __restrict__ W0h,
    const f16* __restrict__ W1h, const f16* __restrict__ W2h,
    const float* __restrict__ ac0, const float* __restrict__ s1g,
    const float* __restrict__ g1, const float* __restrict__ b1,
    float* __restrict__ maxbuf, float* __restrict__ s2g){
  __shared__ f16 sW0[2048];
  __shared__ f16 sW1[4096];
  __shared__ float ac0c[64];
  __shared__ f16 ac1s[128];
  __shared__ f16 hb0[4][16][72];
  __shared__ f16 hb1[4][2][16][72];
  float (*redbuf)[256] = (float(*)[256])hb0;       // overlay (hb0 dead by then)
  const int tid = threadIdx.x;
  const int lane = tid & 63, wv = tid >> 6;
  const int e16 = lane & 15, q = lane >> 4;
  *(f16x8*)(&sW0[tid*8]) = *(const f16x8*)(W0h + tid*8);
  *(f16x8*)(&sW1[tid*8])        = *(const f16x8*)(W1h + tid*8);
  *(f16x8*)(&sW1[2048 + tid*8]) = *(const f16x8*)(W1h + 2048 + tid*8);
  if (tid < 64) ac0c[tid] = ac0[64+tid];
  if (tid < 64){
    const float inv = 1.f/(float)TOT;
    float m = s1g[tid]*inv;
    float vv = s1g[64+tid]*inv - m*m;
    float a = g1[tid]*rsqrtf(vv + BN_EPS);
    ac1s[tid]    = (f16)a;
    ac1s[64+tid] = (f16)fmaf(-m, a, b1[tid]);
  }
  __syncthreads();

  f16x8 Bw[8][2];                                  // W2 frags, persistent (regs)
  #pragma unroll
  for (int nt=0;nt<8;nt++)
    #pragma unroll
    for (int s=0;s<2;s++) Bw[nt][s] = *(const f16x8*)(W2h + (nt*16+e16)*64 + s*32 + q*8);

  float ssum[8], ssq[8];
  #pragma unroll
  for (int i=0;i<8;i++){ ssum[i]=0.f; ssq[i]=0.f; }

  #pragma unroll 1
  for (int qq=0; qq<2; ++qq){                      // 2 queries per wave
    const int qid = blockIdx.x*8 + wv*2 + qq;
    // phase 1: h1 tiles for mt=0,1 into hb1
    #pragma unroll 1
    for (int mt=0; mt<2; ++mt){
      int elem = qid*32 + mt*16 + e16;
      f16x8 bg = {};
      if (q < 2) bg = *(const f16x8*)(g16 + (size_t)elem*16 + q*8);
      #pragma unroll
      for (int m=0;m<4;m++){
        f32x4 acc = *(const f32x4*)(&ac0c[m*16 + q*4]);
        f16x8 A0f = *(const f16x8*)(&sW0[(m*16+e16)*32 + q*8]);
        acc = __builtin_amdgcn_mfma_f32_16x16x32_f16(A0f, bg, acc, 0,0,0);
        f16x4 w;
        w[0]=(f16)fmaxf(acc[0],0.f); w[1]=(f16)fmaxf(acc[1],0.f);
        w[2]=(f16)fmaxf(acc[2],0.f); w[3]=(f16)fmaxf(acc[3],0.f);
        *(f16x4*)(&hb0[wv][e16][m*16 + q*4]) = w;
      }
      f32x4 acc2[4];
      #pragma unroll
      for (int m=0;m<4;m++) acc2[m] = (f32x4){0.f,0.f,0.f,0.f};
      #pragma unroll
      for (int s=0;s<2;s++){
        f16x8 bh = *(const f16x8*)(&hb0[wv][e16][s*32 + q*8]);
        #pragma unroll
        for (int m=0;m<4;m++){
          f16x8 A1f = *(const f16x8*)(&sW1[(m*16+e16)*64 + s*32 + q*8]);
          acc2[m] = __builtin_amdgcn_mfma_f32_16x16x32_f16(A1f, bh, acc2[m], 0,0,0);
        }
      }
      #pragma unroll
      for (int m=0;m<4;m++){
        f16x4 a4 = *(const f16x4*)(&ac1s[m*16 + q*4]);
        f16x4 c4 = *(const f16x4*)(&ac1s[64 + m*16 + q*4]);
        f16x2 p0 = bnrelu2((f16x2){(f16)acc2[m][0], (f16)acc2[m][1]},
                           (f16x2){a4[0],a4[1]}, (f16x2){c4[0],c4[1]});
        f16x2 p1 = bnrelu2((f16x2){(f16)acc2[m][2], (f16)acc2[m][3]},
                           (f16x2){a4[2],a4[3]}, (f16x2){c4[2],c4[3]});
        f16x4 w; w[0]=p0[0]; w[1]=p0[1]; w[2]=p1[0]; w[3]=p1[1];
        *(f16x4*)(&hb1[wv][mt][e16][m*16 + q*4]) = w;
      }
    }
    // phase 2: GEMM3, nt in 2 groups of 4 — FULLY UNROLLED (const indices)
    float mx[8];
    #pragma unroll
    for (int g=0; g<2; ++g){
      f32x4 acc3[4][2];
      #pragma unroll
      for (int j=0;j<4;j++){ acc3[j][0]=(f32x4){0,0,0,0}; acc3[j][1]=(f32x4){0,0,0,0}; }
      #pragma unroll
      for (int mt=0; mt<2; ++mt)
        #pragma unroll
        for (int s=0;s<2;s++){
          f16x8 af = *(const f16x8*)(&hb1[wv][mt][e16][s*32 + q*8]);
          #pragma unroll
          for (int j=0;j<4;j++)
            acc3[j][mt] = __builtin_amdgcn_mfma_f32_16x16x32_f16(af, Bw[g*4+j][s], acc3[j][mt], 0,0,0);
        }
      #pragma unroll
      for (int j=0;j<4;j++){
        int nt = g*4 + j;
        f32x4 u = acc3[j][0], vv = acc3[j][1];
        float m1 = fmaxf(fmaxf(u[0],u[1]), fmaxf(u[2],u[3]));
        float m2 = fmaxf(fmaxf(vv[0],vv[1]), fmaxf(vv[2],vv[3]));
        float m = fmaxf(m1, m2);
        ssum[nt] += (u[0]+u[1])+(u[2]+u[3]) + (vv[0]+vv[1])+(vv[2]+vv[3]);
        float sq = 0.f;
        #pragma unroll
        for (int i=0;i<4;i++){ sq = fmaf(u[i],u[i],sq); sq = fmaf(vv[i],vv[i],sq); }
        ssq[nt] += sq;
        m = fmaxf(m, __shfl_xor(m, 16, 64));
        m = fmaxf(m, __shfl_xor(m, 32, 64));
        mx[nt] = m;
      }
    }
    if (lane < 16){
      #pragma unroll
      for (int nt=0;nt<8;nt++) maxbuf[(size_t)qid*128 + nt*16 + lane] = mx[nt];
    }
  }
  #pragma unroll
  for (int nt=0;nt<8;nt++){
    ssum[nt] += __shfl_xor(ssum[nt], 16, 64);
    ssum[nt] += __shfl_xor(ssum[nt], 32, 64);
    ssq[nt]  += __shfl_xor(ssq[nt], 16, 64);
    ssq[nt]  += __shfl_xor(ssq[nt], 32, 64);
  }
  __syncthreads();                                 // all hb0 reads done before overlay
  if (q==0){
    #pragma unroll
    for (int nt=0;nt<8;nt++){
      redbuf[wv][nt*16+e16]     = ssum[nt];
      redbuf[wv][128+nt*16+e16] = ssq[nt];
    }
  }
  __syncthreads();
  float v = redbuf[0][tid]+redbuf[1][tid]+redbuf[2][tid]+redbuf[3][tid];
  atomicAdd(&s2g[tid], v);
}

// K6: per-block BN2 finalize (from s2g) + out = relu(a2*max + c2)
__global__ __launch_bounds__(256) void apply2(
    const float* __restrict__ maxbuf, const float* __restrict__ s2g,
    const float* __restrict__ g2, const float* __restrict__ b2,
    float* __restrict__ outp){
  __shared__ float a2s[128], c2s[128];
  const int tid = threadIdx.x;
  if (tid < 128){
    const float inv = 1.f/(float)TOT;
    float m = s2g[tid]*inv;
    float v = s2g[128+tid]*inv - m*m;
    float a = g2[tid]*rsqrtf(v + BN_EPS);
    a2s[tid] = a;
    c2s[tid] = fmaf(-m, a, b2[tid]);
  }
  __syncthreads();
  int i = blockIdx.x*256 + tid;                    // 1048576
  int o = i & 127;
  outp[i] = fmaxf(fmaf(maxbuf[i], a2s[o], c2s[o]), 0.f);
}

extern "C" void kernel_launch(void* const* d_in, const int* in_sizes, int n_in,
                              void* d_out, int out_size, void* d_ws, size_t ws_size,
                              hipStream_t stream){
  const float* xyz = (const float*)d_in[0];
  const float* pts = (const float*)d_in[1];
  const float* W0  = (const float*)d_in[2];
  const float* g0  = (const float*)d_in[3];
  const float* b0  = (const float*)d_in[4];
  const float* W1  = (const float*)d_in[5];
  const float* g1  = (const float*)d_in[6];
  const float* b1  = (const float*)d_in[7];
  const float* W2  = (const float*)d_in[8];
  const float* g2  = (const float*)d_in[9];
  const float* b2  = (const float*)d_in[10];
  float* out = (float*)d_out;

  float* ws      = (float*)d_ws;
  f16*   grouped = (f16*)ws;                         // 9*TOT f16 SoA
  f16*   g16     = (f16*)(ws + (size_t)5*TOT);       // 16*TOT f16 [elem][16]
  float* maxbuf  = ws + (size_t)13*TOT;              // 4*TOT
  float4* xyzp   = (float4*)(ws + (size_t)17*TOT);   // 32768 float4
  float* basep   = ws + (size_t)17*TOT + 131072;
  f16*   W0h     = (f16*)basep;                      // 2048 f16
  f16*   W1h     = (f16*)(basep + 1024);             // 4096 f16
  f16*   W2h     = (f16*)(basep + 3072);             // 8192 f16
  float* s0m     = basep + 7168;                     // 160
  float* s1g     = s0m + 160;                        // 128
  float* s2g     = s1g + 128;                        // 256 (contig memset 544)
  float* ac0     = s2g + 256;                        // 128

  (void)hipMemsetAsync(s0m, 0, 544*sizeof(float), stream);
  prep      <<< 128, 256, 0, stream>>>(xyz, xyzp);
  knn_gather<<<1024, 256, 0, stream>>>(xyzp, pts, grouped, g16, out);
  stats0m   <<< 128, 256, 0, stream>>>(grouped, s0m);
  finalize0 <<<   1, 256, 0, stream>>>(s0m, W0, g0, b0, ac0, W1, W2, W0h, W1h, W2h);
  layer1s   <<<1024, 256, 0, stream>>>(g16, W0h, W1h, ac0, s1g);
  layer2max <<<1024, 256, 0, stream>>>(g16, W0h, W1h, W2h, ac0, s1g, g1, b1, maxbuf, s2g);
  apply2    <<<4096, 256, 0, stream>>>(maxbuf, s2g, g2, b2, out + 24576);
}

// Round 13
// 197.807 us; speedup vs baseline: 1.0978x; 1.0268x over previous
//
#include <hip/hip_runtime.h>
#include <float.h>
#include <stdint.h>

// B=8, N=4096, S=1024 queries/batch, K=32 neighbors
#define TOT   262144      // 8*1024*32 grouped elements
#define NPTS  4096
#define KNN   32
#define BN_EPS 1e-5f
#define CAPV  64          // kNN fast-path candidate capacity (1 per lane)
#define TILEP 2048        // kNN LDS tile points (32 KB)

typedef _Float16 f16;
typedef _Float16 f16x2 __attribute__((ext_vector_type(2)));
typedef _Float16 f16x4 __attribute__((ext_vector_type(4)));
typedef _Float16 f16x8 __attribute__((ext_vector_type(8)));
typedef float    f32x4 __attribute__((ext_vector_type(4)));

__device__ __forceinline__ int mbcnt64(unsigned long long m){
  return __builtin_amdgcn_mbcnt_hi((unsigned)(m>>32),
         __builtin_amdgcn_mbcnt_lo((unsigned)(m & 0xffffffffull), 0));
}
__device__ __forceinline__ unsigned f2ord(float f){
  unsigned u = __float_as_uint(f);
  return u ^ (((unsigned)((int)u >> 31)) | 0x80000000u);
}
// packed bn+relu on 2 f16 halves
__device__ __forceinline__ f16x2 bnrelu2(f16x2 x, f16x2 a, f16x2 c){
  f16x2 r = x*a + c;
  const f16 z = (f16)0.f;
  r[0] = r[0] > z ? r[0] : z;
  r[1] = r[1] > z ? r[1] : z;
  return r;
}
// write one gathered element: SoA f16 (stats gram) + [elem][16] (MFMA B-frags)
__device__ __forceinline__ void writeElem(int n, int e, float qx, float qy, float qz,
    const float* __restrict__ xb3, const float* __restrict__ fb,
    f16* __restrict__ grouped, f16* __restrict__ g16){
  float px = xb3[n*3+0], py = xb3[n*3+1], pz = xb3[n*3+2];
  f16 a[16];
  a[0]=(f16)(px-qx); a[1]=(f16)(py-qy); a[2]=(f16)(pz-qz);
  #pragma unroll
  for (int c6=0;c6<6;c6++) a[3+c6] = (f16)fb[n*6+c6];
  #pragma unroll
  for (int i=9;i<16;i++) a[i]=(f16)0.f;
  #pragma unroll
  for (int c=0;c<9;c++) grouped[c*TOT+e] = a[c];
  f16x8 lo, hi;
  #pragma unroll
  for (int i=0;i<8;i++){ lo[i]=a[i]; hi[i]=a[8+i]; }
  *(f16x8*)(g16 + (size_t)e*16)     = lo;
  *(f16x8*)(g16 + (size_t)e*16 + 8) = hi;
}

// K1: block = 4 waves = 8 queries (2/wave), grid 1024. prep fused: |p|^2
// computed during staging from raw xyz (no xyzp buffer/kernel). Tile = 2048
// pts (32 KB); each pass = 2 staging rounds. Pass A: per-lane min -> joint
// bitonic -> Uf bound. Pass B: re-stage, LDS-atomic compact d<=Uf. Joint u64
// bitonic of (f2ord(d),idx) -> exact top-32 (jax.lax.top_k tie order).
__global__ __launch_bounds__(256) void knn_gather(
    const float* __restrict__ xyz, const float* __restrict__ pts,
    f16* __restrict__ grouped, f16* __restrict__ g16,
    float* __restrict__ out_newxyz){
  __shared__ float4 tile[TILEP];                   // 32 KB
  __shared__ unsigned wk[8][CAPV];
  __shared__ unsigned short wi[8][CAPV];
  __shared__ unsigned lcnt[8];
  const int tid = threadIdx.x, lane = tid & 63, wv = tid >> 6;
  const int q0 = blockIdx.x*8 + wv*2;              // wave's 2 queries
  const int b  = (blockIdx.x*8) >> 10;             // same batch for block
  const float* xb3 = xyz + (size_t)b*NPTS*3;
  float qx[2],qy[2],qz[2],qq[2];
  #pragma unroll
  for (int t=0;t<2;t++){
    int n = ((q0+t) & 1023)*4;                     // stride 4096/1024
    qx[t]=xb3[n*3+0]; qy[t]=xb3[n*3+1]; qz[t]=xb3[n*3+2];
    qq[t]=qx[t]*qx[t]+qy[t]*qy[t]+qz[t]*qz[t];
  }
  if (tid < 8) lcnt[tid] = 0;
  if (lane == 0){
    #pragma unroll
    for (int t=0;t<2;t++){
      out_newxyz[(q0+t)*3+0]=qx[t]; out_newxyz[(q0+t)*3+1]=qy[t];
      out_newxyz[(q0+t)*3+2]=qz[t];
    }
  }

  // pass A: per-lane min distance over this lane's 64 points (2 rounds x 32)
  float dmin[2] = {FLT_MAX, FLT_MAX};
  #pragma unroll 1
  for (int r=0; r<2; ++r){
    __syncthreads();
    #pragma unroll
    for (int k=0;k<8;k++){
      int p = r*TILEP + k*256 + tid;
      float x = xb3[p*3+0], y = xb3[p*3+1], z = xb3[p*3+2];
      tile[k*256+tid] = make_float4(x,y,z, x*x+y*y+z*z);
    }
    __syncthreads();
    #pragma unroll 4
    for (int i=0;i<32;i++){
      float4 P = tile[i*64+lane];
      #pragma unroll
      for (int t=0;t<2;t++){
        float d = (qq[t]+P.w) - 2.f*(qx[t]*P.x+qy[t]*P.y+qz[t]*P.z);
        dmin[t] = d < dmin[t] ? d : dmin[t];
      }
    }
  }
  // joint float bitonic sort of minima ascending
  float sm[2] = {dmin[0], dmin[1]};
  #pragma unroll
  for (int k=2;k<=64;k<<=1){
    #pragma unroll
    for (int j=k>>1;j>0;j>>=1){
      bool keepmin = (((lane&k)==0) == ((lane&j)==0));
      #pragma unroll
      for (int t=0;t<2;t++){
        float o = __shfl_xor(sm[t], j, 64);
        sm[t] = keepmin ? fminf(sm[t],o) : fmaxf(sm[t],o);
      }
    }
  }
  float Uf[2];
  #pragma unroll
  for (int t=0;t<2;t++) Uf[t] = __shfl(sm[t], 31, 64);

  // pass B: re-stage rounds; compact candidates d<=Uf (order-free)
  #pragma unroll 1
  for (int r=0; r<2; ++r){
    __syncthreads();
    #pragma unroll
    for (int k=0;k<8;k++){
      int p = r*TILEP + k*256 + tid;
      float x = xb3[p*3+0], y = xb3[p*3+1], z = xb3[p*3+2];
      tile[k*256+tid] = make_float4(x,y,z, x*x+y*y+z*z);
    }
    __syncthreads();
    #pragma unroll 2
    for (int i=0;i<32;i++){
      float4 P = tile[i*64+lane];
      #pragma unroll
      for (int t=0;t<2;t++){
        float d = (qq[t]+P.w) - 2.f*(qx[t]*P.x+qy[t]*P.y+qz[t]*P.z);
        if (d <= Uf[t]){
          unsigned p2 = atomicAdd(&lcnt[wv*2+t], 1u);
          if (p2 < CAPV){
            wk[wv*2+t][p2] = f2ord(d);
            wi[wv*2+t][p2] = (unsigned short)(r*TILEP + i*64 + lane);
          }
        }
      }
    }
  }
  int cnt[2] = {(int)lcnt[wv*2], (int)lcnt[wv*2+1]};

  // joint u64 bitonic of (key<<16)|idx
  unsigned long long v[2];
  #pragma unroll
  for (int t=0;t<2;t++){
    unsigned myk = (lane<cnt[t]) ? wk[wv*2+t][lane] : 0xFFFFFFFFu;
    unsigned myi = (lane<cnt[t]) ? wi[wv*2+t][lane] : 0u;
    v[t] = (((unsigned long long)myk)<<16) | myi;
  }
  #pragma unroll
  for (int k=2;k<=64;k<<=1){
    #pragma unroll
    for (int j=k>>1;j>0;j>>=1){
      bool keepmin = (((lane&k)==0) == ((lane&j)==0));
      #pragma unroll
      for (int t=0;t<2;t++){
        unsigned long long o = __shfl_xor(v[t], j, 64);
        v[t] = keepmin ? (v[t]<o?v[t]:o) : (v[t]>o?v[t]:o);
      }
    }
  }

  const float* fb = pts + (size_t)b*NPTS*6;
  #pragma unroll 1
  for (int t=0;t<2;t++){
    const int ebase = (q0+t)*KNN;
    if (cnt[t] <= CAPV){
      if (lane < KNN){
        int n = (int)(v[t] & 0xffffull);
        writeElem(n, ebase+lane, qx[t],qy[t],qz[t], xb3, fb, grouped, g16);
      }
    } else {
      // slow exact path (rare): global rescan, radix bisect + ordered collect
      unsigned V=0;
      for (int bit=31; bit>=0; --bit){
        unsigned X = V | (1u<<bit);
        int c=0;
        for (int j=0;j<64;j++){
          int n = j*64+lane;
          float px=xb3[n*3], py=xb3[n*3+1], pz=xb3[n*3+2];
          float d = qq[t] + (px*px+py*py+pz*pz)
                  - 2.f*(qx[t]*px+qy[t]*py+qz[t]*pz);
          c += __popcll(__ballot(f2ord(d) < X));
        }
        if (c < KNN) V = X;
      }
      int cnt2=0;
      for (int pass=0; pass<2; ++pass){
        for (int j=0;j<64;j++){
          int n = j*64+lane;
          float px=xb3[n*3], py=xb3[n*3+1], pz=xb3[n*3+2];
          float d = qq[t] + (px*px+py*py+pz*pz)
                  - 2.f*(qx[t]*px+qy[t]*py+qz[t]*pz);
          unsigned kk = f2ord(d);
          bool sel = pass ? (kk==V) : (kk<V);
          unsigned long long msk = __ballot(sel);
          int pos = cnt2 + mbcnt64(msk);
          if (sel && pos < KNN)
            writeElem(n, ebase+pos, qx[t],qy[t],qz[t], xb3, fb, grouped, g16);
          cnt2 += __popcll(msk);
        }
      }
    }
  }
}

// K2: second-moment matrix via MFMA gram. G' = [g(9ch), 1]; M = G'^T G'.
// Coverage: 128 blocks x 4 waves x 16 chunks x 32 elems = 262144 = TOT.
__global__ __launch_bounds__(256) void stats0m(const f16* __restrict__ grouped,
    float* __restrict__ s0m){
  const int lane = threadIdx.x & 63, wv = threadIdx.x >> 6;
  const int c = lane & 15, q = lane >> 4;
  const int base = (blockIdx.x*4 + wv)*512;        // 512 elems per wave
  f16x8 cfill = {};
  if (c == 9){
    #pragma unroll
    for (int i=0;i<8;i++) cfill[i] = (f16)1.f;
  }
  f32x4 acc = {0.f,0.f,0.f,0.f};
  #pragma unroll 4
  for (int chunk=0; chunk<16; ++chunk){
    int e = base + chunk*32 + q*8;
    f16x8 f = cfill;
    if (c < 9) f = *(const f16x8*)(grouped + (size_t)c*TOT + e);
    acc = __builtin_amdgcn_mfma_f32_16x16x32_f16(f, f, acc, 0,0,0);
  }
  __shared__ float red[4][16][16];
  #pragma unroll
  for (int i=0;i<4;i++) red[wv][q*4+i][c] = acc[i];
  __syncthreads();
  const int tid = threadIdx.x;
  if (tid < 160){
    int row = tid>>4, col = tid&15;
    float vv = red[0][row][col]+red[1][row][col]+red[2][row][col]+red[3][row][col];
    atomicAdd(&s0m[tid], vv);
  }
}

// K3: M(10x16) -> BN0 coeffs; W0h = a0-folded W0 (f16 [64][32] K-pad); W1h/W2h f16
__global__ void finalize0(const float* __restrict__ s0m,
    const float* __restrict__ W0, const float* __restrict__ g0,
    const float* __restrict__ b0, float* __restrict__ ac0,
    const float* __restrict__ W1, const float* __restrict__ W2,
    f16* __restrict__ W0h, f16* __restrict__ W1h, f16* __restrict__ W2h){
  const int tid = threadIdx.x;                     // 256
  __shared__ float S[160];
  __shared__ float A0s[64];
  if (tid < 160) S[tid] = s0m[tid];
  __syncthreads();
  if (tid < 64){
    float w[9];
    #pragma unroll
    for (int c=0;c<9;c++) w[c]=W0[tid*9+c];
    const float inv = 1.f/(float)TOT;
    float m=0.f;
    #pragma unroll
    for (int c=0;c<9;c++) m = fmaf(w[c], S[c*16+9], m);
    m *= inv;
    float e2=0.f;
    #pragma unroll
    for (int c1=0;c1<9;c1++){
      float t=0.f;
      #pragma unroll
      for (int c2=0;c2<9;c2++) t = fmaf(w[c2], S[c1*16+c2], t);
      e2 = fmaf(w[c1], t, e2);
    }
    e2 *= inv;
    float var = e2 - m*m;
    float a = g0[tid]*rsqrtf(var + BN_EPS);
    ac0[tid]    = a;
    ac0[64+tid] = fmaf(-m, a, b0[tid]);
    A0s[tid]    = a;
  }
  __syncthreads();
  for (int i=tid; i<2048; i+=256){
    int o = i>>5, c = i&31;
    W0h[i] = (f16)(c<9 ? A0s[o]*W0[o*9+c] : 0.f);
  }
  for (int i=tid; i<4096; i+=256) W1h[i] = (f16)W1[i];
  for (int i=tid; i<8192; i+=256) W2h[i] = (f16)W2[i];
}

// K4: BN1-stats only, grid 1024 (4 subs/wave). Weights staged in LDS.
__global__ __launch_bounds__(256, 2) void layer1s(
    const f16* __restrict__ g16, const f16* __restrict__ W0h,
    const f16* __restrict__ W1h, const float* __restrict__ ac0,
    float* __restrict__ s1g){
  __shared__ f16 sW0[2048];
  __shared__ f16 sW1[4096];
  __shared__ float ac0c[64];
  __shared__ f16 hb0[4][16][72];
  __shared__ float sred[4][128];
  const int tid = threadIdx.x;
  const int lane = tid & 63, wv = tid >> 6;
  const int e16 = lane & 15, q = lane >> 4;
  *(f16x8*)(&sW0[tid*8]) = *(const f16x8*)(W0h + tid*8);
  *(f16x8*)(&sW1[tid*8])        = *(const f16x8*)(W1h + tid*8);
  *(f16x8*)(&sW1[2048 + tid*8]) = *(const f16x8*)(W1h + 2048 + tid*8);
  if (tid < 64) ac0c[tid] = ac0[64+tid];
  __syncthreads();

  const int base = blockIdx.x*256 + wv*64;         // grid 1024
  float ssum[16], ssq[16];
  #pragma unroll
  for (int i=0;i<16;i++){ ssum[i]=0.f; ssq[i]=0.f; }

  #pragma unroll 1
  for (int sub=0; sub<4; ++sub){
    int elem = base + sub*16 + e16;
    f16x8 bg = {};
    if (q < 2) bg = *(const f16x8*)(g16 + (size_t)elem*16 + q*8);
    #pragma unroll
    for (int m=0;m<4;m++){
      f32x4 acc = *(const f32x4*)(&ac0c[m*16 + q*4]);
      f16x8 A0f = *(const f16x8*)(&sW0[(m*16+e16)*32 + q*8]);
      acc = __builtin_amdgcn_mfma_f32_16x16x32_f16(A0f, bg, acc, 0,0,0);
      f16x4 w;
      w[0]=(f16)fmaxf(acc[0],0.f); w[1]=(f16)fmaxf(acc[1],0.f);
      w[2]=(f16)fmaxf(acc[2],0.f); w[3]=(f16)fmaxf(acc[3],0.f);
      *(f16x4*)(&hb0[wv][e16][m*16 + q*4]) = w;
    }
    f32x4 acc2[4];
    #pragma unroll
    for (int m=0;m<4;m++) acc2[m] = (f32x4){0.f,0.f,0.f,0.f};
    #pragma unroll
    for (int s=0;s<2;s++){
      f16x8 bh = *(const f16x8*)(&hb0[wv][e16][s*32 + q*8]);
      #pragma unroll
      for (int m=0;m<4;m++){
        f16x8 A1f = *(const f16x8*)(&sW1[(m*16+e16)*64 + s*32 + q*8]);
        acc2[m] = __builtin_amdgcn_mfma_f32_16x16x32_f16(A1f, bh, acc2[m], 0,0,0);
      }
    }
    #pragma unroll
    for (int m=0;m<4;m++)
      #pragma unroll
      for (int i=0;i<4;i++){
        float x = acc2[m][i];
        ssum[m*4+i] += x;
        ssq[m*4+i]  = fmaf(x, x, ssq[m*4+i]);
      }
  }
  #pragma unroll
  for (int t=0;t<16;t++){
    float a = ssum[t], bq = ssq[t];
    #pragma unroll
    for (int off=1; off<16; off<<=1){
      a  += __shfl_xor(a,  off, 64);
      bq += __shfl_xor(bq, off, 64);
    }
    ssum[t]=a; ssq[t]=bq;
  }
  if (e16==0){
    #pragma unroll
    for (int m=0;m<4;m++)
      #pragma unroll
      for (int i=0;i<4;i++){
        int ch = m*16 + q*4 + i;
        sred[wv][ch]    = ssum[m*4+i];
        sred[wv][64+ch] = ssq[m*4+i];
      }
  }
  __syncthreads();
  if (tid < 128){
    float v = sred[0][tid]+sred[1][tid]+sred[2][tid]+sred[3][tid];
    atomicAdd(&s1g[tid], v);
  }
}

// K5: recompute x1 (weights from LDS), BN1+relu, GEMM3 vs W2 (fully unrolled
// nt groups -> const indices, arrays in regs). Max over k + BN2 stats fused.
__global__ __launch_bounds__(256, 2) void layer2max(
    const f16* __restrict__ g16, const f16* __restrict__ W0h,
    const f16* __restrict__ W1h, const f16* __restrict__ W2h,
    const float* __restrict__ ac0, const float* __restrict__ s1g,
    const float* __restrict__ g1, const float* __restrict__ b1,
    float* __restrict__ maxbuf, float* __restrict__ s2g){
  __shared__ f16 sW0[2048];
  __shared__ f16 sW1[4096];
  __shared__ float ac0c[64];
  __shared__ f16 ac1s[128];
  __shared__ f16 hb0[4][16][72];
  __shared__ f16 hb1[4][2][16][72];
  float (*redbuf)[256] = (float(*)[256])hb0;       // overlay (hb0 dead by then)
  const int tid = threadIdx.x;
  const int lane = tid & 63, wv = tid >> 6;
  const int e16 = lane & 15, q = lane >> 4;
  *(f16x8*)(&sW0[tid*8]) = *(const f16x8*)(W0h + tid*8);
  *(f16x8*)(&sW1[tid*8])        = *(const f16x8*)(W1h + tid*8);
  *(f16x8*)(&sW1[2048 + tid*8]) = *(const f16x8*)(W1h + 2048 + tid*8);
  if (tid < 64) ac0c[tid] = ac0[64+tid];
  if (tid < 64){
    const float inv = 1.f/(float)TOT;
    float m = s1g[tid]*inv;
    float vv = s1g[64+tid]*inv - m*m;
    float a = g1[tid]*rsqrtf(vv + BN_EPS);
    ac1s[tid]    = (f16)a;
    ac1s[64+tid] = (f16)fmaf(-m, a, b1[tid]);
  }
  __syncthreads();

  f16x8 Bw[8][2];                                  // W2 frags, persistent (regs)
  #pragma unroll
  for (int nt=0;nt<8;nt++)
    #pragma unroll
    for (int s=0;s<2;s++) Bw[nt][s] = *(const f16x8*)(W2h + (nt*16+e16)*64 + s*32 + q*8);

  float ssum[8], ssq[8];
  #pragma unroll
  for (int i=0;i<8;i++){ ssum[i]=0.f; ssq[i]=0.f; }

  #pragma unroll 1
  for (int qq=0; qq<2; ++qq){                      // 2 queries per wave
    const int qid = blockIdx.x*8 + wv*2 + qq;
    // phase 1: h1 tiles for mt=0,1 into hb1
    #pragma unroll 1
    for (int mt=0; mt<2; ++mt){
      int elem = qid*32 + mt*16 + e16;
      f16x8 bg = {};
      if (q < 2) bg = *(const f16x8*)(g16 + (size_t)elem*16 + q*8);
      #pragma unroll
      for (int m=0;m<4;m++){
        f32x4 acc = *(const f32x4*)(&ac0c[m*16 + q*4]);
        f16x8 A0f = *(const f16x8*)(&sW0[(m*16+e16)*32 + q*8]);
        acc = __builtin_amdgcn_mfma_f32_16x16x32_f16(A0f, bg, acc, 0,0,0);
        f16x4 w;
        w[0]=(f16)fmaxf(acc[0],0.f); w[1]=(f16)fmaxf(acc[1],0.f);
        w[2]=(f16)fmaxf(acc[2],0.f); w[3]=(f16)fmaxf(acc[3],0.f);
        *(f16x4*)(&hb0[wv][e16][m*16 + q*4]) = w;
      }
      f32x4 acc2[4];
      #pragma unroll
      for (int m=0;m<4;m++) acc2[m] = (f32x4){0.f,0.f,0.f,0.f};
      #pragma unroll
      for (int s=0;s<2;s++){
        f16x8 bh = *(const f16x8*)(&hb0[wv][e16][s*32 + q*8]);
        #pragma unroll
        for (int m=0;m<4;m++){
          f16x8 A1f = *(const f16x8*)(&sW1[(m*16+e16)*64 + s*32 + q*8]);
          acc2[m] = __builtin_amdgcn_mfma_f32_16x16x32_f16(A1f, bh, acc2[m], 0,0,0);
        }
      }
      #pragma unroll
      for (int m=0;m<4;m++){
        f16x4 a4 = *(const f16x4*)(&ac1s[m*16 + q*4]);
        f16x4 c4 = *(const f16x4*)(&ac1s[64 + m*16 + q*4]);
        f16x2 p0 = bnrelu2((f16x2){(f16)acc2[m][0], (f16)acc2[m][1]},
                           (f16x2){a4[0],a4[1]}, (f16x2){c4[0],c4[1]});
        f16x2 p1 = bnrelu2((f16x2){(f16)acc2[m][2], (f16)acc2[m][3]},
                           (f16x2){a4[2],a4[3]}, (f16x2){c4[2],c4[3]});
        f16x4 w; w[0]=p0[0]; w[1]=p0[1]; w[2]=p1[0]; w[3]=p1[1];
        *(f16x4*)(&hb1[wv][mt][e16][m*16 + q*4]) = w;
      }
    }
    // phase 2: GEMM3, nt in 2 groups of 4 — fully unrolled (const indices)
    float mx[8];
    #pragma unroll
    for (int g=0; g<2; ++g){
      f32x4 acc3[4][2];
      #pragma unroll
      for (int j=0;j<4;j++){ acc3[j][0]=(f32x4){0,0,0,0}; acc3[j][1]=(f32x4){0,0,0,0}; }
      #pragma unroll
      for (int mt=0; mt<2; ++mt)
        #pragma unroll
        for (int s=0;s<2;s++){
          f16x8 af = *(const f16x8*)(&hb1[wv][mt][e16][s*32 + q*8]);
          #pragma unroll
          for (int j=0;j<4;j++)
            acc3[j][mt] = __builtin_amdgcn_mfma_f32_16x16x32_f16(af, Bw[g*4+j][s], acc3[j][mt], 0,0,0);
        }
      #pragma unroll
      for (int j=0;j<4;j++){
        int nt = g*4 + j;
        f32x4 u = acc3[j][0], vv = acc3[j][1];
        float m1 = fmaxf(fmaxf(u[0],u[1]), fmaxf(u[2],u[3]));
        float m2 = fmaxf(fmaxf(vv[0],vv[1]), fmaxf(vv[2],vv[3]));
        float m = fmaxf(m1, m2);
        ssum[nt] += (u[0]+u[1])+(u[2]+u[3]) + (vv[0]+vv[1])+(vv[2]+vv[3]);
        float sq = 0.f;
        #pragma unroll
        for (int i=0;i<4;i++){ sq = fmaf(u[i],u[i],sq); sq = fmaf(vv[i],vv[i],sq); }
        ssq[nt] += sq;
        m = fmaxf(m, __shfl_xor(m, 16, 64));
        m = fmaxf(m, __shfl_xor(m, 32, 64));
        mx[nt] = m;
      }
    }
    if (lane < 16){
      #pragma unroll
      for (int nt=0;nt<8;nt++) maxbuf[(size_t)qid*128 + nt*16 + lane] = mx[nt];
    }
  }
  #pragma unroll
  for (int nt=0;nt<8;nt++){
    ssum[nt] += __shfl_xor(ssum[nt], 16, 64);
    ssum[nt] += __shfl_xor(ssum[nt], 32, 64);
    ssq[nt]  += __shfl_xor(ssq[nt], 16, 64);
    ssq[nt]  += __shfl_xor(ssq[nt], 32, 64);
  }
  __syncthreads();                                 // all hb0 reads done before overlay
  if (q==0){
    #pragma unroll
    for (int nt=0;nt<8;nt++){
      redbuf[wv][nt*16+e16]     = ssum[nt];
      redbuf[wv][128+nt*16+e16] = ssq[nt];
    }
  }
  __syncthreads();
  float v = redbuf[0][tid]+redbuf[1][tid]+redbuf[2][tid]+redbuf[3][tid];
  atomicAdd(&s2g[tid], v);
}

// K6: per-block BN2 finalize + out = relu(a2*max + c2), float4-vectorized
__global__ __launch_bounds__(256) void apply2(
    const float4* __restrict__ maxbuf4, const float* __restrict__ s2g,
    const float* __restrict__ g2, const float* __restrict__ b2,
    float4* __restrict__ outp4){
  __shared__ float a2s[128], c2s[128];
  const int tid = threadIdx.x;
  if (tid < 128){
    const float inv = 1.f/(float)TOT;
    float m = s2g[tid]*inv;
    float v = s2g[128+tid]*inv - m*m;
    float a = g2[tid]*rsqrtf(v + BN_EPS);
    a2s[tid] = a;
    c2s[tid] = fmaf(-m, a, b2[tid]);
  }
  __syncthreads();
  int i = blockIdx.x*256 + tid;                    // 262144 float4
  int c4 = (i & 31)*4;
  float4 m = maxbuf4[i];
  float4 r;
  r.x = fmaxf(fmaf(m.x, a2s[c4+0], c2s[c4+0]), 0.f);
  r.y = fmaxf(fmaf(m.y, a2s[c4+1], c2s[c4+1]), 0.f);
  r.z = fmaxf(fmaf(m.z, a2s[c4+2], c2s[c4+2]), 0.f);
  r.w = fmaxf(fmaf(m.w, a2s[c4+3], c2s[c4+3]), 0.f);
  outp4[i] = r;
}

extern "C" void kernel_launch(void* const* d_in, const int* in_sizes, int n_in,
                              void* d_out, int out_size, void* d_ws, size_t ws_size,
                              hipStream_t stream){
  const float* xyz = (const float*)d_in[0];
  const float* pts = (const float*)d_in[1];
  const float* W0  = (const float*)d_in[2];
  const float* g0  = (const float*)d_in[3];
  const float* b0  = (const float*)d_in[4];
  const float* W1  = (const float*)d_in[5];
  const float* g1  = (const float*)d_in[6];
  const float* b1  = (const float*)d_in[7];
  const float* W2  = (const float*)d_in[8];
  const float* g2  = (const float*)d_in[9];
  const float* b2  = (const float*)d_in[10];
  float* out = (float*)d_out;

  float* ws      = (float*)d_ws;
  f16*   grouped = (f16*)ws;                         // 9*TOT f16 SoA
  f16*   g16     = (f16*)(ws + (size_t)5*TOT);       // 16*TOT f16 [elem][16]
  float* maxbuf  = ws + (size_t)13*TOT;              // 4*TOT
  float* basep   = ws + (size_t)17*TOT;
  f16*   W0h     = (f16*)basep;                      // 2048 f16
  f16*   W1h     = (f16*)(basep + 1024);             // 4096 f16
  f16*   W2h     = (f16*)(basep + 3072);             // 8192 f16
  float* s0m     = basep + 7168;                     // 160
  float* s1g     = s0m + 160;                        // 128
  float* s2g     = s1g + 128;                        // 256 (contig memset 544)
  float* ac0     = s2g + 256;                        // 128

  (void)hipMemsetAsync(s0m, 0, 544*sizeof(float), stream);
  knn_gather<<<1024, 256, 0, stream>>>(xyz, pts, grouped, g16, out);
  stats0m   <<< 128, 256, 0, stream>>>(grouped, s0m);
  finalize0 <<<   1, 256, 0, stream>>>(s0m, W0, g0, b0, ac0, W1, W2, W0h, W1h, W2h);
  layer1s   <<<1024, 256, 0, stream>>>(g16, W0h, W1h, ac0, s1g);
  layer2max <<<1024, 256, 0, stream>>>(g16, W0h, W1h, W2h, ac0, s1g, g1, b1, maxbuf, s2g);
  apply2    <<<1024, 256, 0, stream>>>((const float4*)maxbuf, s2g, g2, b2, (float4*)(out + 24576));
}